// Round 7
// baseline (267.780 us; speedup 1.0000x reference)
//
#include <hip/hip_runtime.h>
#include <math.h>

// Problem dims (fixed by the reference)
#define ED 16      // EDGE_DIM
#define HD 32      // HIDDEN (== NODE_DIM == in_channels)
#define OD 32      // OUT_DIM
#define KD 1024    // HD*OD
#define EPB 256    // edges per block
#define TPW 4      // 16-edge tiles per wave
#define HPAD 40    // padded LDS row stride (halfwords) for h (16B-aligned rows)
#define XPAD 33    // padded LDS row stride (floats) for x rows (conflict-free)

typedef float  f32x4  __attribute__((ext_vector_type(4)));
typedef float  v4f    __attribute__((ext_vector_type(4)));
typedef short  bf16x8 __attribute__((ext_vector_type(8)));

// Workspace layout (byte offsets; all 16B aligned)
//  [0)      W1fT   512 f32   [c][j] transposed, bn1-scaled
//  [2048)   b1f     32 f32
//  [2176)   bfold 1024 f32   folded layer-2 bias, natural k order
//  [6272)   wsAhi 32768 bf16 W2fT hi, frag-linear: q = g*512 + lane*8 + idx
//                             -> value W2fT[k=g*16+(lane&15)][j=(lane>>4)*8+idx]
//  [71808)  wsAlo 32768 bf16 W2fT lo, same order
constexpr size_t WS_BYTES = 137344;

// LDS layout for edge_kernel (byte offsets into smem[], all 16B aligned)
constexpr int LOFF_H    = 0;        // hHi[EPB*HPAD] hw, hLo follows; xS overlay
constexpr int LOFF_HLO  = EPB * HPAD * 2;            // 20480
constexpr int LOFF_WHI  = EPB * HPAD * 4;            // 40960: wLhi 32768 B
constexpr int LOFF_WLO  = LOFF_WHI + 32768;          // 73728: wLlo 32768 B
constexpr int LOFF_W1T  = LOFF_WLO + 32768;          // 106496: 2048 B
constexpr int LOFF_B1   = LOFF_W1T + 2048;           // 108544: 128 B
constexpr int LOFF_BF   = LOFF_B1 + 128;             // 108672: 2048 B (512 f32, this k-half)
constexpr int LOFF_SRC  = LOFF_BF + 2048;            // 110720: 1024 B
constexpr int LOFF_DST  = LOFF_SRC + 1024;           // 111744: 1024 B
constexpr int LDS_TOTAL = LOFF_DST + 1024;           // 112768 B (< 160 KiB)

__device__ inline void bf16_split(float v, unsigned short& hi, unsigned short& lo) {
    unsigned int b = __float_as_uint(v);
    hi = (unsigned short)(b >> 16);
    float hif = __uint_as_float((unsigned int)hi << 16);
    float lof = v - hif;
    lo = (unsigned short)(__float_as_uint(lof) >> 16);
}

// ---------------------------------------------------------------------------
// Prep: fold BN into weights/biases. W2 traversed in SOURCE-linear order
// (coalesced reads), scattered 2B fire-and-forget writes to frag-linear dest.
// ---------------------------------------------------------------------------
__global__ void prep_kernel(const float* __restrict__ W1, const float* __restrict__ b1,
                            const float* __restrict__ g1, const float* __restrict__ be1,
                            const float* __restrict__ m1, const float* __restrict__ v1,
                            const float* __restrict__ W2, const float* __restrict__ b2,
                            const float* __restrict__ g2, const float* __restrict__ be2,
                            const float* __restrict__ m2, const float* __restrict__ v2,
                            unsigned char* __restrict__ wsb)
{
    float* w1t = (float*)(wsb);
    float* b1f = (float*)(wsb + 2048);
    float* bf  = (float*)(wsb + 2176);
    unsigned short* ahi = (unsigned short*)(wsb + 6272);
    unsigned short* alo = (unsigned short*)(wsb + 71808);

    int t = blockIdx.x * blockDim.x + threadIdx.x;
    int stride = gridDim.x * blockDim.x;

    for (int q = t; q < HD * ED; q += stride) {       // W1fT [c][j]
        int c = q >> 4, j = q & 15;
        float s = g1[c] / sqrtf(v1[c] + 1e-5f);
        w1t[q] = W1[j * HD + c] * s;
    }
    for (int c = t; c < HD; c += stride) {
        float s = g1[c] / sqrtf(v1[c] + 1e-5f);
        b1f[c] = b1[c] * s + be1[c] - m1[c] * s;
    }
    for (int k = t; k < KD; k += stride) {
        float s = g2[k] / sqrtf(v2[k] + 1e-5f);
        bf[k] = b2[k] * s + be2[k] - m2[k] * s;
    }
    // p = j*KD + k : coalesced read of W2 and g2/v2
    for (int p = t; p < KD * HD; p += stride) {
        int j = p >> 10, k = p & 1023;
        float s = g2[k] / sqrtf(v2[k] + 1e-5f);
        float v = W2[p] * s;
        int g = k >> 4, m = k & 15;
        int quad = j >> 3, idx = j & 7;
        int q = g * 512 + (quad * 16 + m) * 8 + idx;  // frag-linear dest
        unsigned short hi, lo;
        bf16_split(v, hi, lo);
        ahi[q] = hi;
        alo[q] = lo;
    }
}

// ---------------------------------------------------------------------------
// Root: out = x @ root + bias, LDS-staged (root + 8 x-rows per block).
// Also initializes all of d_out before edge atomics land.
// ---------------------------------------------------------------------------
__global__ __launch_bounds__(256)
void root_kernel(const float* __restrict__ x, const float* __restrict__ root,
                 const float* __restrict__ bias, float* __restrict__ out, int nN)
{
    __shared__ __align__(16) float rootS[HD * OD];   // 4 KB
    __shared__ __align__(16) float biasS[OD];
    __shared__ float xsh[8][XPAD];

    const int t = threadIdx.x;
    ((v4f*)rootS)[t] = ((const v4f*)root)[t];        // 256 v4f = 1024 f
    if (t < 8) ((v4f*)biasS)[t] = ((const v4f*)bias)[t];

    const int nodeBase = blockIdx.x * 8;
    if (t < 64) {
        int nl = t >> 3, q = t & 7;
        int node = nodeBase + nl;
        if (node >= nN) node = nN - 1;
        v4f v = ((const v4f*)(x + (size_t)node * HD))[q];
        xsh[nl][4 * q + 0] = v.x;
        xsh[nl][4 * q + 1] = v.y;
        xsh[nl][4 * q + 2] = v.z;
        xsh[nl][4 * q + 3] = v.w;
    }
    __syncthreads();

    const int nl = t >> 5, o = t & 31;
    const int node = nodeBase + nl;
    if (node >= nN) return;
    float acc = biasS[o];
#pragma unroll
    for (int i = 0; i < HD; ++i)
        acc = fmaf(xsh[nl][i], rootS[i * OD + o], acc);
    out[(size_t)node * OD + o] = acc;
}

// ---------------------------------------------------------------------------
// Fused edge kernel v7 (LDS-resident weights, k-split gridDim.y=2):
//  Block (bx, s): edges [bx*256, bx*256+256), output channels [16s, 16s+16).
//  Staging: this k-half's W2 frags (hi+lo, 64 KB) + bias half into LDS once.
//  Phase 1: one edge/thread, h = LReLU(ea@W1f+b1f) (duplicated across the 2
//           y-blocks — cheap), hi/lo split -> LDS.
//  Phase 2: main loop is 100% LDS + MFMA: per i, 2 ds_read_b128 (A hi/lo,
//           shared by all 4 edge-tiles) + 12 MFMA + LReLU/contract VALU.
//           No global access in the loop at all.
//  Epilogue: 16 atomicAdd per edge per block.
//  LDS 110 KB -> 1 block/CU (by design: latency source removed, TLP not
//  needed for L2; 4 independent MFMA chains cover MFMA latency, unroll-4
//  covers LDS latency via compiler lgkmcnt(N) scheduling).
// ---------------------------------------------------------------------------
__global__ __launch_bounds__(256)
void edge_kernel(const float* __restrict__ x, const int* __restrict__ eidx,
                 const float* __restrict__ ea_g, const unsigned char* __restrict__ wsb,
                 float* __restrict__ out, int nE)
{
    __shared__ __align__(16) unsigned char smem[LDS_TOTAL];
    unsigned short* hHi = (unsigned short*)(smem + LOFF_H);    // [EPB][HPAD]
    unsigned short* hLo = (unsigned short*)(smem + LOFF_HLO);
    float*          xS  = (float*)(smem + LOFF_H);             // overlay: [EPB][XPAD]
    unsigned short* wLhi = (unsigned short*)(smem + LOFF_WHI); // [32][64][8]
    unsigned short* wLlo = (unsigned short*)(smem + LOFF_WLO);
    float* w1t = (float*)(smem + LOFF_W1T);
    float* b1s = (float*)(smem + LOFF_B1);
    float* bfL = (float*)(smem + LOFF_BF);                     // [32][16] this half
    int*  srcS = (int*)(smem + LOFF_SRC);
    int*  dstS = (int*)(smem + LOFF_DST);

    const int t = threadIdx.x;
    const int s = blockIdx.y;                                  // k-half / o-half
    const float* wsW1 = (const float*)(wsb);
    const float* wsB1 = (const float*)(wsb + 2048);
    const float* wsBf = (const float*)(wsb + 2176);
    const unsigned short* wsAhi = (const unsigned short*)(wsb + 6272);
    const unsigned short* wsAlo = (const unsigned short*)(wsb + 71808);

    // ---- issue per-edge input loads first (long latency, overlap staging) --
    int e = blockIdx.x * EPB + t;
    int ec = (e < nE) ? e : (nE - 1);
    int my_src = __builtin_nontemporal_load(eidx + ec);
    int my_dst = __builtin_nontemporal_load(eidx + nE + ec);

    const v4f* xrow_p = (const v4f*)(x + (size_t)my_src * HD);
    v4f xrow[8];
#pragma unroll
    for (int q = 0; q < 8; ++q) xrow[q] = xrow_p[q];

    const v4f* eap = (const v4f*)(ea_g + (size_t)ec * ED);
    v4f a0 = __builtin_nontemporal_load(eap + 0);
    v4f a1 = __builtin_nontemporal_load(eap + 1);
    v4f a2 = __builtin_nontemporal_load(eap + 2);
    v4f a3 = __builtin_nontemporal_load(eap + 3);

    srcS[t] = my_src;
    dstS[t] = my_dst;

    // ---- stage small tables ----
    if (t < 128)      ((v4f*)w1t)[t] = ((const v4f*)wsW1)[t];
    else if (t < 136) ((v4f*)b1s)[t - 128] = ((const v4f*)wsB1)[t - 128];
    if (t < 128) {    // bias half: bfL[i*16+m] = bfold[(2i+s)*16+m]
        ((v4f*)bfL)[t] = ((const v4f*)wsBf)[(t >> 2) * 8 + s * 4 + (t & 3)];
    }

    // ---- stage this half's weight frags: 8 v4f hi + 8 v4f lo per thread ----
    {
        const v4f* srcHi = (const v4f*)wsAhi;    // v4f = 8 halfwords
        const v4f* srcLo = (const v4f*)wsAlo;
        v4f* dstHi = (v4f*)wLhi;
        v4f* dstLo = (v4f*)wLlo;
#pragma unroll
        for (int p = 0; p < 8; ++p) {
            int c = t + p * 256;                          // dst chunk: i*64+lane
            int sc = (2 * (c >> 6) + s) * 64 + (c & 63);  // src chunk: g*64+lane
            dstHi[c] = srcHi[sc];
            dstLo[c] = srcLo[sc];
        }
    }

    __syncthreads();   // (1) tables + weights ready

    // ---- layer 1 into registers ----
    float hreg[HD];
#pragma unroll
    for (int c = 0; c < HD; ++c) {
        const v4f* r4 = (const v4f*)(w1t + c * ED);
        v4f w0 = r4[0], w1 = r4[1], w2 = r4[2], w3 = r4[3];
        float acc = b1s[c];
        acc = fmaf(a0.x, w0.x, acc); acc = fmaf(a0.y, w0.y, acc);
        acc = fmaf(a0.z, w0.z, acc); acc = fmaf(a0.w, w0.w, acc);
        acc = fmaf(a1.x, w1.x, acc); acc = fmaf(a1.y, w1.y, acc);
        acc = fmaf(a1.z, w1.z, acc); acc = fmaf(a1.w, w1.w, acc);
        acc = fmaf(a2.x, w2.x, acc); acc = fmaf(a2.y, w2.y, acc);
        acc = fmaf(a2.z, w2.z, acc); acc = fmaf(a2.w, w2.w, acc);
        acc = fmaf(a3.x, w3.x, acc); acc = fmaf(a3.y, w3.y, acc);
        acc = fmaf(a3.z, w3.z, acc); acc = fmaf(a3.w, w3.w, acc);
        hreg[c] = fmaxf(acc, 0.01f * acc);
    }

    // ---- pack hi/lo, store to padded LDS rows ----
#pragma unroll
    for (int ch = 0; ch < 4; ++ch) {
        bf16x8 phi, plo;
#pragma unroll
        for (int u = 0; u < 8; ++u) {
            unsigned short hi, lo;
            bf16_split(hreg[ch * 8 + u], hi, lo);
            phi[u] = (short)hi;
            plo[u] = (short)lo;
        }
        *(bf16x8*)(hHi + t * HPAD + ch * 8) = phi;
        *(bf16x8*)(hLo + t * HPAD + ch * 8) = plo;
    }
    __syncthreads();   // (2) h ready

    // ---- B-frags LDS -> regs ----
    const int wave = t >> 6;
    const int lane = t & 63;
    const int n = lane & 15;       // C column = edge within tile
    const int quad = lane >> 4;
    const int ebase = wave * 64;   // wave's first edge in block

    bf16x8 bHi[TPW], bLo[TPW];
#pragma unroll
    for (int tt = 0; tt < TPW; ++tt) {
        int edge = ebase + tt * 16 + n;
        bHi[tt] = *(const bf16x8*)(hHi + edge * HPAD + quad * 8);
        bLo[tt] = *(const bf16x8*)(hLo + edge * HPAD + quad * 8);
    }

    int xdst[TPW];
    bool evalid[TPW];
    int xoff[TPW];
#pragma unroll
    for (int tt = 0; tt < TPW; ++tt) {
        int le = ebase + tt * 16 + n;
        evalid[tt] = (blockIdx.x * EPB + le) < nE;
        xdst[tt] = dstS[le];
        xoff[tt] = le * XPAD;
    }

    __syncthreads();   // (3) everyone done reading h LDS

    // ---- overlay: write x rows into xS ----
#pragma unroll
    for (int q = 0; q < 8; ++q) {
        v4f v = xrow[q];
        xS[t * XPAD + 4 * q + 0] = v.x;
        xS[t * XPAD + 4 * q + 1] = v.y;
        xS[t * XPAD + 4 * q + 2] = v.z;
        xS[t * XPAD + 4 * q + 3] = v.w;
    }
    __syncthreads();   // (4) xS ready

    f32x4 msg[TPW];
#pragma unroll
    for (int tt = 0; tt < TPW; ++tt)
        msg[tt] = (f32x4){0.f, 0.f, 0.f, 0.f};

    // ---- main loop: pure LDS + MFMA ----
#pragma unroll 4
    for (int i = 0; i < HD; ++i) {
        const bf16x8 cH = *(const bf16x8*)(wLhi + (i * 64 + lane) * 8);
        const bf16x8 cL = *(const bf16x8*)(wLlo + (i * 64 + lane) * 8);
        const f32x4 b0 = *(const f32x4*)(bfL + i * 16 + quad * 4);
        float xv[TPW];
#pragma unroll
        for (int tt = 0; tt < TPW; ++tt) xv[tt] = xS[xoff[tt] + i];

#pragma unroll
        for (int tt = 0; tt < TPW; ++tt) {
            f32x4 c = b0;
            c = __builtin_amdgcn_mfma_f32_16x16x32_bf16(cL, bHi[tt], c, 0, 0, 0);
            c = __builtin_amdgcn_mfma_f32_16x16x32_bf16(cH, bLo[tt], c, 0, 0, 0);
            c = __builtin_amdgcn_mfma_f32_16x16x32_bf16(cH, bHi[tt], c, 0, 0, 0);
            f32x4 w = __builtin_elementwise_max(c, 0.01f * c);   // LeakyReLU
            f32x4 xs = {xv[tt], xv[tt], xv[tt], xv[tt]};
            msg[tt] = __builtin_elementwise_fma(xs, w, msg[tt]);
        }
    }

    // ---- scatter: out[dst][o], o = s*16 + quad*4 + r ----
#pragma unroll
    for (int tt = 0; tt < TPW; ++tt) {
        if (!evalid[tt]) continue;
        float* op = out + (size_t)xdst[tt] * OD + s * 16 + quad * 4;
#pragma unroll
        for (int r = 0; r < 4; ++r)
            atomicAdd(op + r, msg[tt][r]);
    }
}

// ---------------------------------------------------------------------------
// Fallback (ws too small): correctness path only (VALU, raw weights).
// ---------------------------------------------------------------------------
__global__ __launch_bounds__(64)
void edge_kernel_raw(const float* __restrict__ x, const int* __restrict__ eidx,
                     const float* __restrict__ ea_g,
                     const float* __restrict__ W1, const float* __restrict__ b1,
                     const float* __restrict__ g1, const float* __restrict__ be1,
                     const float* __restrict__ m1, const float* __restrict__ v1,
                     const float* __restrict__ W2, const float* __restrict__ b2,
                     const float* __restrict__ g2, const float* __restrict__ be2,
                     const float* __restrict__ m2, const float* __restrict__ v2,
                     float* __restrict__ out, int nE)
{
    int e = blockIdx.x * 64 + threadIdx.x;
    if (e >= nE) return;
    const int obase = blockIdx.y * 16;

    int src = eidx[e];
    int dst = eidx[nE + e];

    float ea[ED];
#pragma unroll
    for (int j = 0; j < ED; ++j) ea[j] = ea_g[(size_t)e * ED + j];

    float h[HD];
#pragma unroll
    for (int c = 0; c < HD; ++c) {
        float acc = b1[c];
#pragma unroll
        for (int j = 0; j < ED; ++j) acc = fmaf(ea[j], W1[j * HD + c], acc);
        float s = g1[c] / sqrtf(v1[c] + 1e-5f);
        acc = (acc - m1[c]) * s + be1[c];
        h[c] = fmaxf(acc, 0.01f * acc);
    }

    float msg[16];
#pragma unroll
    for (int o = 0; o < 16; ++o) msg[o] = 0.f;

    const float* xj = x + (size_t)src * HD;
    for (int i = 0; i < HD; ++i) {
        float xv = xj[i];
#pragma unroll
        for (int oo = 0; oo < 16; ++oo) {
            int k = i * OD + obase + oo;
            float acc = b2[k];
#pragma unroll
            for (int j = 0; j < HD; ++j) acc = fmaf(h[j], W2[j * KD + k], acc);
            float s = g2[k] / sqrtf(v2[k] + 1e-5f);
            acc = (acc - m2[k]) * s + be2[k];
            float w = fmaxf(acc, 0.01f * acc);
            msg[oo] = fmaf(xv, w, msg[oo]);
        }
    }

    float* op = out + (size_t)dst * OD + obase;
#pragma unroll
    for (int oo = 0; oo < 16; ++oo) atomicAdd(op + oo, msg[oo]);
}

// ---------------------------------------------------------------------------
extern "C" void kernel_launch(void* const* d_in, const int* in_sizes, int n_in,
                              void* d_out, int out_size, void* d_ws, size_t ws_size,
                              hipStream_t stream)
{
    const float* x    = (const float*)d_in[0];
    const int*   eidx = (const int*)  d_in[1];
    const float* ea   = (const float*)d_in[2];
    // d_in[3] = batch (unused)
    const float* W1   = (const float*)d_in[4];
    const float* b1   = (const float*)d_in[5];
    const float* g1   = (const float*)d_in[6];
    const float* be1  = (const float*)d_in[7];
    const float* m1   = (const float*)d_in[8];
    const float* v1   = (const float*)d_in[9];
    const float* W2   = (const float*)d_in[10];
    const float* b2   = (const float*)d_in[11];
    const float* g2   = (const float*)d_in[12];
    const float* be2  = (const float*)d_in[13];
    const float* m2   = (const float*)d_in[14];
    const float* v2   = (const float*)d_in[15];
    const float* root = (const float*)d_in[16];
    const float* bias = (const float*)d_in[17];
    float* out = (float*)d_out;

    int nN = in_sizes[0] / HD;
    int nE = in_sizes[2] / ED;

    root_kernel<<<dim3((nN + 7) / 8), 256, 0, stream>>>(x, root, bias, out, nN);

    if (ws_size >= WS_BYTES) {
        unsigned char* wsb = (unsigned char*)d_ws;
        prep_kernel<<<128, 256, 0, stream>>>(W1, b1, g1, be1, m1, v1,
                                             W2, b2, g2, be2, m2, v2, wsb);
        int nblk = (nE + EPB - 1) / EPB;
        edge_kernel<<<dim3(nblk, 2), 256, 0, stream>>>(x, eidx, ea, wsb, out, nE);
    } else {
        edge_kernel_raw<<<dim3((nE + 63) / 64, 2), 64, 0, stream>>>(
            x, eidx, ea, W1, b1, g1, be1, m1, v1,
            W2, b2, g2, be2, m2, v2, out, nE);
    }
}

// Round 8
// 224.687 us; speedup vs baseline: 1.1918x; 1.1918x over previous
//
#include <hip/hip_runtime.h>
#include <math.h>

// Problem dims (fixed by the reference)
#define ED 16      // EDGE_DIM
#define HD 32      // HIDDEN (== NODE_DIM == in_channels)
#define OD 32      // OUT_DIM
#define KD 1024    // HD*OD
#define EPB 256    // edges per block
#define TPW 4      // 16-edge tiles per wave
#define HPAD 40    // padded LDS row stride (halfwords) for h (16B-aligned rows)
#define XPAD 36    // padded LDS row stride (floats) for x rows (16B-aligned, 2-way-free)

typedef float  f32x4  __attribute__((ext_vector_type(4)));
typedef float  v4f    __attribute__((ext_vector_type(4)));
typedef short  bf16x8 __attribute__((ext_vector_type(8)));

// Workspace layout (byte offsets; all 16B aligned)
//  [0)      W1fT   512 f32   [c][j] transposed, bn1-scaled
//  [2048)   b1f     32 f32
//  [2176)   bfold 1024 f32   folded layer-2 bias, natural k order
//  [6272)   wsAhi 32768 bf16 W2fT hi, frag-linear: q = g*512 + lane*8 + idx
//                             -> value W2fT[k=g*16+(lane&15)][j=(lane>>4)*8+idx]
//           (no lo plane: W2-lo compensation dropped; h-lo kept)
constexpr size_t WS_BYTES = 71808;

// LDS layout for edge_kernel (byte offsets; all 16B aligned). Total 80000 B
// -> exactly 2 blocks/CU on the 160 KiB LDS (the design constraint).
constexpr int LOFF_H    = 0;                         // hHi [EPB][HPAD] hw
constexpr int LOFF_HLO  = EPB * HPAD * 2;            // 20480: hLo
constexpr int LOFF_WHI  = EPB * HPAD * 4;            // 40960: wLhi 32768 B (o-half)
constexpr int LOFF_W1T  = LOFF_WHI + 32768;          // 73728: 2048 B
constexpr int LOFF_B1   = LOFF_W1T + 2048;           // 75776: 128 B
constexpr int LOFF_BF   = LOFF_B1 + 128;             // 75904: 2048 B (512 f32, this o-half)
constexpr int LOFF_SRC  = LOFF_BF + 2048;            // 77952: 1024 B
constexpr int LOFF_DST  = LOFF_SRC + 1024;           // 78976: 1024 B
constexpr int LDS_TOTAL = LOFF_DST + 1024;           // 80000 B

__device__ inline void bf16_split(float v, unsigned short& hi, unsigned short& lo) {
    unsigned int b = __float_as_uint(v);
    hi = (unsigned short)(b >> 16);
    float hif = __uint_as_float((unsigned int)hi << 16);
    float lof = v - hif;
    lo = (unsigned short)(__float_as_uint(lof) >> 16);
}

// ---------------------------------------------------------------------------
// Fused prep+root kernel (one launch fewer; both must precede edge_kernel).
//  blocks [0, nRootBlk): out = x @ root + bias (8 nodes/block, LDS-staged)
//  blocks [nRootBlk, nRootBlk+128): BN-fold weights into ws (hi plane only)
// ---------------------------------------------------------------------------
__global__ __launch_bounds__(256)
void prep_root_kernel(const float* __restrict__ x, const float* __restrict__ root,
                      const float* __restrict__ bias, float* __restrict__ out, int nN,
                      int nRootBlk,
                      const float* __restrict__ W1, const float* __restrict__ b1,
                      const float* __restrict__ g1, const float* __restrict__ be1,
                      const float* __restrict__ m1, const float* __restrict__ v1,
                      const float* __restrict__ W2, const float* __restrict__ b2,
                      const float* __restrict__ g2, const float* __restrict__ be2,
                      const float* __restrict__ m2, const float* __restrict__ v2,
                      unsigned char* __restrict__ wsb)
{
    const int t = threadIdx.x;
    if ((int)blockIdx.x >= nRootBlk) {
        // ---------------- prep path ----------------
        float* w1t = (float*)(wsb);
        float* b1f = (float*)(wsb + 2048);
        float* bf  = (float*)(wsb + 2176);
        unsigned short* ahi = (unsigned short*)(wsb + 6272);

        int bt = ((int)blockIdx.x - nRootBlk) * blockDim.x + t;
        int stride = 128 * blockDim.x;

        for (int q = bt; q < HD * ED; q += stride) {       // W1fT [c][j]
            int c = q >> 4, j = q & 15;
            float s = g1[c] / sqrtf(v1[c] + 1e-5f);
            w1t[q] = W1[j * HD + c] * s;
        }
        for (int c = bt; c < HD; c += stride) {
            float s = g1[c] / sqrtf(v1[c] + 1e-5f);
            b1f[c] = b1[c] * s + be1[c] - m1[c] * s;
        }
        for (int k = bt; k < KD; k += stride) {
            float s = g2[k] / sqrtf(v2[k] + 1e-5f);
            bf[k] = b2[k] * s + be2[k] - m2[k] * s;
        }
        // p = j*KD + k : coalesced read of W2/g2/v2; scattered 2B writes
        for (int p = bt; p < KD * HD; p += stride) {
            int j = p >> 10, k = p & 1023;
            float s = g2[k] / sqrtf(v2[k] + 1e-5f);
            float v = W2[p] * s;
            int g = k >> 4, m = k & 15;
            int quad = j >> 3, idx = j & 7;
            int q = g * 512 + (quad * 16 + m) * 8 + idx;  // frag-linear dest
            ahi[q] = (unsigned short)(__float_as_uint(v) >> 16);
        }
        return;
    }

    // ---------------- root path ----------------
    __shared__ __align__(16) float rootS[HD * OD];   // 4 KB
    __shared__ __align__(16) float biasS[OD];
    __shared__ float xsh[8][XPAD];

    ((v4f*)rootS)[t] = ((const v4f*)root)[t];        // 256 v4f = 1024 f
    if (t < 8) ((v4f*)biasS)[t] = ((const v4f*)bias)[t];

    const int nodeBase = blockIdx.x * 8;
    if (t < 64) {
        int nl = t >> 3, q = t & 7;
        int node = nodeBase + nl;
        if (node >= nN) node = nN - 1;
        v4f v = ((const v4f*)(x + (size_t)node * HD))[q];
        xsh[nl][4 * q + 0] = v.x;
        xsh[nl][4 * q + 1] = v.y;
        xsh[nl][4 * q + 2] = v.z;
        xsh[nl][4 * q + 3] = v.w;
    }
    __syncthreads();

    const int nl = t >> 5, o = t & 31;
    const int node = nodeBase + nl;
    if (node >= nN) return;
    float acc = biasS[o];
#pragma unroll
    for (int i = 0; i < HD; ++i)
        acc = fmaf(xsh[nl][i], rootS[i * OD + o], acc);
    out[(size_t)node * OD + o] = acc;
}

// ---------------------------------------------------------------------------
// Fused edge kernel v8 (LDS-resident hi weights, o-half split, 2 blocks/CU):
//  Block (bx, s): edges [bx*256, +256), output channels [16s, 16s+16).
//  Staging: this o-half's W2-hi frags (32 KB) + bias half into LDS once.
//  Phase 1: one edge/thread, h = LReLU(ea@W1f+b1f), hi/lo split -> LDS.
//  Phase 2: 100% LDS + MFMA loop: per i, 1 ds_read_b128 (A-hi, shared by all
//           4 edge-tiles) + 8 MFMA (2 per tile: aHi*bLo + aHi*bHi — h-side
//           compensation kept, W2-lo dropped) + LReLU/contract VALU.
//  Epilogue: 16 atomicAdd per edge per block.
//  LDS 80000 B -> 2 blocks/CU (8 waves): staging/barrier/epilogue phases of
//  one block overlap the other block's MFMA loop.
// ---------------------------------------------------------------------------
__global__ __launch_bounds__(256, 2)
void edge_kernel(const float* __restrict__ x, const int* __restrict__ eidx,
                 const float* __restrict__ ea_g, const unsigned char* __restrict__ wsb,
                 float* __restrict__ out, int nE)
{
    __shared__ __align__(16) unsigned char smem[LDS_TOTAL];
    unsigned short* hHi = (unsigned short*)(smem + LOFF_H);    // [EPB][HPAD]
    unsigned short* hLo = (unsigned short*)(smem + LOFF_HLO);
    float*          xS  = (float*)(smem + LOFF_H);             // overlay: [EPB][XPAD]
    unsigned short* wLhi = (unsigned short*)(smem + LOFF_WHI); // [32][64][8]
    float* w1t = (float*)(smem + LOFF_W1T);
    float* b1s = (float*)(smem + LOFF_B1);
    float* bfL = (float*)(smem + LOFF_BF);                     // [32][16] this half
    int*  srcS = (int*)(smem + LOFF_SRC);
    int*  dstS = (int*)(smem + LOFF_DST);

    const int t = threadIdx.x;
    const int s = blockIdx.y;                                  // o-half
    const float* wsW1 = (const float*)(wsb);
    const float* wsB1 = (const float*)(wsb + 2048);
    const float* wsBf = (const float*)(wsb + 2176);
    const unsigned short* wsAhi = (const unsigned short*)(wsb + 6272);

    // ---- issue per-edge input loads first (long latency, overlap staging) --
    int e = blockIdx.x * EPB + t;
    int ec = (e < nE) ? e : (nE - 1);
    int my_src = __builtin_nontemporal_load(eidx + ec);
    int my_dst = __builtin_nontemporal_load(eidx + nE + ec);

    const v4f* xrow_p = (const v4f*)(x + (size_t)my_src * HD);
    v4f xrow[8];
#pragma unroll
    for (int q = 0; q < 8; ++q) xrow[q] = xrow_p[q];

    const v4f* eap = (const v4f*)(ea_g + (size_t)ec * ED);
    v4f a0 = __builtin_nontemporal_load(eap + 0);
    v4f a1 = __builtin_nontemporal_load(eap + 1);
    v4f a2 = __builtin_nontemporal_load(eap + 2);
    v4f a3 = __builtin_nontemporal_load(eap + 3);

    srcS[t] = my_src;
    dstS[t] = my_dst;

    // ---- stage small tables ----
    if (t < 128)      ((v4f*)w1t)[t] = ((const v4f*)wsW1)[t];
    else if (t < 136) ((v4f*)b1s)[t - 128] = ((const v4f*)wsB1)[t - 128];
    if (t < 128) {    // bias half: bfL[i*16+m] = bfold[i*32 + s*16 + m]
        ((v4f*)bfL)[t] = ((const v4f*)wsBf)[(t >> 2) * 8 + s * 4 + (t & 3)];
    }

    // ---- stage this o-half's hi weight frags: 8 v4f per thread (32 KB) ----
    {
        const v4f* srcHi = (const v4f*)wsAhi;    // v4f = 8 halfwords
        v4f* dstHi = (v4f*)wLhi;
#pragma unroll
        for (int p = 0; p < 8; ++p) {
            int c = t + p * 256;                          // dst chunk: i*64 + v4fidx
            int sc = (2 * (c >> 6) + s) * 64 + (c & 63);  // src chunk: g*64 + v4fidx
            dstHi[c] = srcHi[sc];
        }
    }

    __syncthreads();   // (1) tables + weights ready

    // ---- layer 1 into registers ----
    float hreg[HD];
#pragma unroll
    for (int c = 0; c < HD; ++c) {
        const v4f* r4 = (const v4f*)(w1t + c * ED);
        v4f w0 = r4[0], w1 = r4[1], w2 = r4[2], w3 = r4[3];
        float acc = b1s[c];
        acc = fmaf(a0.x, w0.x, acc); acc = fmaf(a0.y, w0.y, acc);
        acc = fmaf(a0.z, w0.z, acc); acc = fmaf(a0.w, w0.w, acc);
        acc = fmaf(a1.x, w1.x, acc); acc = fmaf(a1.y, w1.y, acc);
        acc = fmaf(a1.z, w1.z, acc); acc = fmaf(a1.w, w1.w, acc);
        acc = fmaf(a2.x, w2.x, acc); acc = fmaf(a2.y, w2.y, acc);
        acc = fmaf(a2.z, w2.z, acc); acc = fmaf(a2.w, w2.w, acc);
        acc = fmaf(a3.x, w3.x, acc); acc = fmaf(a3.y, w3.y, acc);
        acc = fmaf(a3.z, w3.z, acc); acc = fmaf(a3.w, w3.w, acc);
        hreg[c] = fmaxf(acc, 0.01f * acc);
    }

    // ---- pack hi/lo, store to padded LDS rows ----
#pragma unroll
    for (int ch = 0; ch < 4; ++ch) {
        bf16x8 phi, plo;
#pragma unroll
        for (int u = 0; u < 8; ++u) {
            unsigned short hi, lo;
            bf16_split(hreg[ch * 8 + u], hi, lo);
            phi[u] = (short)hi;
            plo[u] = (short)lo;
        }
        *(bf16x8*)(hHi + t * HPAD + ch * 8) = phi;
        *(bf16x8*)(hLo + t * HPAD + ch * 8) = plo;
    }
    __syncthreads();   // (2) h ready

    // ---- B-frags LDS -> regs ----
    const int wave = t >> 6;
    const int lane = t & 63;
    const int n = lane & 15;       // C column = edge within tile
    const int quad = lane >> 4;
    const int ebase = wave * 64;   // wave's first edge in block

    bf16x8 bHi[TPW], bLo[TPW];
#pragma unroll
    for (int tt = 0; tt < TPW; ++tt) {
        int edge = ebase + tt * 16 + n;
        bHi[tt] = *(const bf16x8*)(hHi + edge * HPAD + quad * 8);
        bLo[tt] = *(const bf16x8*)(hLo + edge * HPAD + quad * 8);
    }

    int xdst[TPW];
    bool evalid[TPW];
    int xoff[TPW];
#pragma unroll
    for (int tt = 0; tt < TPW; ++tt) {
        int le = ebase + tt * 16 + n;
        evalid[tt] = (blockIdx.x * EPB + le) < nE;
        xdst[tt] = dstS[le];
        xoff[tt] = le * XPAD;
    }

    __syncthreads();   // (3) everyone done reading h LDS

    // ---- overlay: write x rows into xS (b128 stores, 16B-aligned rows) ----
#pragma unroll
    for (int q = 0; q < 8; ++q)
        *(v4f*)(xS + t * XPAD + 4 * q) = xrow[q];
    __syncthreads();   // (4) xS ready

    f32x4 msg[TPW];
#pragma unroll
    for (int tt = 0; tt < TPW; ++tt)
        msg[tt] = (f32x4){0.f, 0.f, 0.f, 0.f};

    // ---- main loop: pure LDS + MFMA (2 MFMA per tile: h-side comp only) ----
#pragma unroll 4
    for (int i = 0; i < HD; ++i) {
        const bf16x8 cH = *(const bf16x8*)(wLhi + (i * 64 + lane) * 8);
        const f32x4 b0 = *(const f32x4*)(bfL + i * 16 + quad * 4);
        float xv[TPW];
#pragma unroll
        for (int tt = 0; tt < TPW; ++tt) xv[tt] = xS[xoff[tt] + i];

#pragma unroll
        for (int tt = 0; tt < TPW; ++tt) {
            f32x4 c = b0;
            c = __builtin_amdgcn_mfma_f32_16x16x32_bf16(cH, bLo[tt], c, 0, 0, 0);
            c = __builtin_amdgcn_mfma_f32_16x16x32_bf16(cH, bHi[tt], c, 0, 0, 0);
            f32x4 w = __builtin_elementwise_max(c, 0.01f * c);   // LeakyReLU
            f32x4 xs = {xv[tt], xv[tt], xv[tt], xv[tt]};
            msg[tt] = __builtin_elementwise_fma(xs, w, msg[tt]);
        }
    }

    // ---- scatter: out[dst][o], o = s*16 + quad*4 + r ----
#pragma unroll
    for (int tt = 0; tt < TPW; ++tt) {
        if (!evalid[tt]) continue;
        float* op = out + (size_t)xdst[tt] * OD + s * 16 + quad * 4;
#pragma unroll
        for (int r = 0; r < 4; ++r)
            atomicAdd(op + r, msg[tt][r]);
    }
}

// ---------------------------------------------------------------------------
// Fallback (ws too small): correctness path only (VALU, raw weights).
// ---------------------------------------------------------------------------
__global__ __launch_bounds__(64)
void edge_kernel_raw(const float* __restrict__ x, const int* __restrict__ eidx,
                     const float* __restrict__ ea_g,
                     const float* __restrict__ W1, const float* __restrict__ b1,
                     const float* __restrict__ g1, const float* __restrict__ be1,
                     const float* __restrict__ m1, const float* __restrict__ v1,
                     const float* __restrict__ W2, const float* __restrict__ b2,
                     const float* __restrict__ g2, const float* __restrict__ be2,
                     const float* __restrict__ m2, const float* __restrict__ v2,
                     float* __restrict__ out, int nE)
{
    int e = blockIdx.x * 64 + threadIdx.x;
    if (e >= nE) return;
    const int obase = blockIdx.y * 16;

    int src = eidx[e];
    int dst = eidx[nE + e];

    float ea[ED];
#pragma unroll
    for (int j = 0; j < ED; ++j) ea[j] = ea_g[(size_t)e * ED + j];

    float h[HD];
#pragma unroll
    for (int c = 0; c < HD; ++c) {
        float acc = b1[c];
#pragma unroll
        for (int j = 0; j < ED; ++j) acc = fmaf(ea[j], W1[j * HD + c], acc);
        float s = g1[c] / sqrtf(v1[c] + 1e-5f);
        acc = (acc - m1[c]) * s + be1[c];
        h[c] = fmaxf(acc, 0.01f * acc);
    }

    float msg[16];
#pragma unroll
    for (int o = 0; o < 16; ++o) msg[o] = 0.f;

    const float* xj = x + (size_t)src * HD;
    for (int i = 0; i < HD; ++i) {
        float xv = xj[i];
#pragma unroll
        for (int oo = 0; oo < 16; ++oo) {
            int k = i * OD + obase + oo;
            float acc = b2[k];
#pragma unroll
            for (int j = 0; j < HD; ++j) acc = fmaf(h[j], W2[j * KD + k], acc);
            float s = g2[k] / sqrtf(v2[k] + 1e-5f);
            acc = (acc - m2[k]) * s + be2[k];
            float w = fmaxf(acc, 0.01f * acc);
            msg[oo] = fmaf(xv, w, msg[oo]);
        }
    }

    float* op = out + (size_t)dst * OD + obase;
#pragma unroll
    for (int oo = 0; oo < 16; ++oo) atomicAdd(op + oo, msg[oo]);
}

// ---------------------------------------------------------------------------
extern "C" void kernel_launch(void* const* d_in, const int* in_sizes, int n_in,
                              void* d_out, int out_size, void* d_ws, size_t ws_size,
                              hipStream_t stream)
{
    const float* x    = (const float*)d_in[0];
    const int*   eidx = (const int*)  d_in[1];
    const float* ea   = (const float*)d_in[2];
    // d_in[3] = batch (unused)
    const float* W1   = (const float*)d_in[4];
    const float* b1   = (const float*)d_in[5];
    const float* g1   = (const float*)d_in[6];
    const float* be1  = (const float*)d_in[7];
    const float* m1   = (const float*)d_in[8];
    const float* v1   = (const float*)d_in[9];
    const float* W2   = (const float*)d_in[10];
    const float* b2   = (const float*)d_in[11];
    const float* g2   = (const float*)d_in[12];
    const float* be2  = (const float*)d_in[13];
    const float* m2   = (const float*)d_in[14];
    const float* v2   = (const float*)d_in[15];
    const float* root = (const float*)d_in[16];
    const float* bias = (const float*)d_in[17];
    float* out = (float*)d_out;

    int nN = in_sizes[0] / HD;
    int nE = in_sizes[2] / ED;

    if (ws_size >= WS_BYTES) {
        unsigned char* wsb = (unsigned char*)d_ws;
        int nRootBlk = (nN + 7) / 8;
        prep_root_kernel<<<dim3(nRootBlk + 128), 256, 0, stream>>>(
            x, root, bias, out, nN, nRootBlk,
            W1, b1, g1, be1, m1, v1, W2, b2, g2, be2, m2, v2, wsb);
        int nblk = (nE + EPB - 1) / EPB;
        edge_kernel<<<dim3(nblk, 2), 256, 0, stream>>>(x, eidx, ea, wsb, out, nE);
    } else {
        prep_root_kernel<<<dim3((nN + 7) / 8), 256, 0, stream>>>(
            x, root, bias, out, nN, (nN + 7) / 8 + 1,   // root path only
            W1, b1, g1, be1, m1, v1, W2, b2, g2, be2, m2, v2, (unsigned char*)d_ws);
        edge_kernel_raw<<<dim3((nE + 63) / 64, 2), 64, 0, stream>>>(
            x, eidx, ea, W1, b1, g1, be1, m1, v1,
            W2, b2, g2, be2, m2, v2, out, nE);
    }
}

// Round 9
// 215.259 us; speedup vs baseline: 1.2440x; 1.0438x over previous
//
#include <hip/hip_runtime.h>
#include <math.h>

// Problem dims (fixed by the reference)
#define ED 16      // EDGE_DIM
#define HD 32      // HIDDEN (== NODE_DIM == in_channels)
#define OD 32      // OUT_DIM
#define KD 1024    // HD*OD
#define EPB 512    // edges per block (8 waves, one o-half per block)
#define TPW 4      // 16-edge tiles per wave
#define HPAD 34    // LDS row stride in halfwords: odd word-stride -> conflict-free

typedef float  f32x4  __attribute__((ext_vector_type(4)));
typedef float  v4f    __attribute__((ext_vector_type(4)));
typedef short  bf16x8 __attribute__((ext_vector_type(8)));

// Workspace layout (byte offsets; all 16B aligned)
//  [0)      W1fT   512 f32   [c][j] transposed, bn1-scaled
//  [2048)   b1f     32 f32
//  [2176)   bfold 1024 f32   folded layer-2 bias, natural k order
//  [6272)   wsAhi 32768 bf16 W2fT hi (RNE), frag-linear:
//           q = g*512 + lane*8 + idx -> W2fT[k=g*16+(lane&15)][j=(lane>>4)*8+idx]
constexpr size_t WS_BYTES = 71808;

// LDS layout for edge_kernel (byte offsets; all 16B aligned). 75904 B total
// -> 2 blocks/CU (the design constraint), 512 thr/block = 4 waves/SIMD.
constexpr int LOFF_HX   = 0;                         // hHi [EPB][HPAD] hw; xS(bf16) overlay
constexpr int LOFF_WHI  = EPB * HPAD * 2;            // 34816: wLhi 32768 B (o-half)
constexpr int LOFF_W1T  = LOFF_WHI + 32768;          // 67584: 2048 B
constexpr int LOFF_B1   = LOFF_W1T + 2048;           // 69632: 128 B
constexpr int LOFF_BF   = LOFF_B1 + 128;             // 69760: 2048 B (512 f32, this o-half)
constexpr int LOFF_SRC  = LOFF_BF + 2048;            // 71808: 2048 B
constexpr int LOFF_DST  = LOFF_SRC + 2048;           // 73856: 2048 B
constexpr int LDS_TOTAL = LOFF_DST + 2048;           // 75904 B

__device__ inline unsigned short bf16_rne(float v) {
    unsigned int u = __float_as_uint(v);
    return (unsigned short)((u + 0x7FFFu + ((u >> 16) & 1u)) >> 16);
}

// ---------------------------------------------------------------------------
// Fused prep+root kernel.
//  blocks [0, nRootBlk): out = x @ root + bias (8 nodes/block, LDS-staged)
//  blocks [nRootBlk, nRootBlk+128): BN-fold weights into ws (hi plane, RNE)
// ---------------------------------------------------------------------------
__global__ __launch_bounds__(256)
void prep_root_kernel(const float* __restrict__ x, const float* __restrict__ root,
                      const float* __restrict__ bias, float* __restrict__ out, int nN,
                      int nRootBlk,
                      const float* __restrict__ W1, const float* __restrict__ b1,
                      const float* __restrict__ g1, const float* __restrict__ be1,
                      const float* __restrict__ m1, const float* __restrict__ v1,
                      const float* __restrict__ W2, const float* __restrict__ b2,
                      const float* __restrict__ g2, const float* __restrict__ be2,
                      const float* __restrict__ m2, const float* __restrict__ v2,
                      unsigned char* __restrict__ wsb)
{
    const int t = threadIdx.x;
    if ((int)blockIdx.x >= nRootBlk) {
        // ---------------- prep path ----------------
        float* w1t = (float*)(wsb);
        float* b1f = (float*)(wsb + 2048);
        float* bf  = (float*)(wsb + 2176);
        unsigned short* ahi = (unsigned short*)(wsb + 6272);

        int bt = ((int)blockIdx.x - nRootBlk) * blockDim.x + t;
        int stride = 128 * blockDim.x;

        for (int q = bt; q < HD * ED; q += stride) {       // W1fT [c][j]
            int c = q >> 4, j = q & 15;
            float s = g1[c] / sqrtf(v1[c] + 1e-5f);
            w1t[q] = W1[j * HD + c] * s;
        }
        for (int c = bt; c < HD; c += stride) {
            float s = g1[c] / sqrtf(v1[c] + 1e-5f);
            b1f[c] = b1[c] * s + be1[c] - m1[c] * s;
        }
        for (int k = bt; k < KD; k += stride) {
            float s = g2[k] / sqrtf(v2[k] + 1e-5f);
            bf[k] = b2[k] * s + be2[k] - m2[k] * s;
        }
        // p = j*KD + k : coalesced read of W2/g2/v2; scattered 2B writes
        for (int p = bt; p < KD * HD; p += stride) {
            int j = p >> 10, k = p & 1023;
            float s = g2[k] / sqrtf(v2[k] + 1e-5f);
            float v = W2[p] * s;
            int g = k >> 4, m = k & 15;
            int quad = j >> 3, idx = j & 7;
            int q = g * 512 + (quad * 16 + m) * 8 + idx;  // frag-linear dest
            ahi[q] = bf16_rne(v);
        }
        return;
    }

    // ---------------- root path ----------------
    __shared__ __align__(16) float rootS[HD * OD];   // 4 KB
    __shared__ __align__(16) float biasS[OD];
    __shared__ float xsh[8][HD + 1];

    ((v4f*)rootS)[t] = ((const v4f*)root)[t];        // 256 v4f = 1024 f
    if (t < 8) ((v4f*)biasS)[t] = ((const v4f*)bias)[t];

    const int nodeBase = blockIdx.x * 8;
    if (t < 64) {
        int nl = t >> 3, q = t & 7;
        int node = nodeBase + nl;
        if (node >= nN) node = nN - 1;
        v4f v = ((const v4f*)(x + (size_t)node * HD))[q];
        xsh[nl][4 * q + 0] = v.x;
        xsh[nl][4 * q + 1] = v.y;
        xsh[nl][4 * q + 2] = v.z;
        xsh[nl][4 * q + 3] = v.w;
    }
    __syncthreads();

    const int nl = t >> 5, o = t & 31;
    const int node = nodeBase + nl;
    if (node >= nN) return;
    float acc = biasS[o];
#pragma unroll
    for (int i = 0; i < HD; ++i)
        acc = fmaf(xsh[nl][i], rootS[i * OD + o], acc);
    out[(size_t)node * OD + o] = acc;
}

// ---------------------------------------------------------------------------
// Fused edge kernel v9 (8-wave blocks, 4 waves/SIMD, single-MFMA tiles):
//  Block (bx, s): edges [bx*512, +512), output channels [16s, 16s+16).
//  Staging: o-half W2-hi frags (32 KB) + tables into LDS once per block.
//  Phase 1: one edge/thread (512 edges), h = LReLU(ea@W1f+b1f), RNE bf16
//           (hi only) -> LDS rows (HPAD=34, conflict-free).
//  Phase 2: pure LDS+MFMA loop: per i, 1 ds_read_b128 (A, shared by all 4
//           tiles) + 4 MFMA + LReLU/contract VALU; x read as bf16 from the
//           dead-h overlay (RNE), bias from LDS.
//  Epilogue: 16 atomicAdd per thread.
//  2 blocks/CU (LDS 75.9 KB), VGPR capped 128 by launch_bounds(512,4).
// ---------------------------------------------------------------------------
__global__ __launch_bounds__(512, 4)
void edge_kernel(const float* __restrict__ x, const int* __restrict__ eidx,
                 const float* __restrict__ ea_g, const unsigned char* __restrict__ wsb,
                 float* __restrict__ out, int nE)
{
    __shared__ __align__(16) unsigned char smem[LDS_TOTAL];
    unsigned short* hHi = (unsigned short*)(smem + LOFF_HX);   // [EPB][HPAD]
    unsigned short* xS  = (unsigned short*)(smem + LOFF_HX);   // overlay (bf16 x)
    unsigned short* wLhi = (unsigned short*)(smem + LOFF_WHI); // [32][64][8]
    float* w1t = (float*)(smem + LOFF_W1T);
    float* b1s = (float*)(smem + LOFF_B1);
    float* bfL = (float*)(smem + LOFF_BF);                     // [32][16] this half
    int*  srcS = (int*)(smem + LOFF_SRC);
    int*  dstS = (int*)(smem + LOFF_DST);

    const int t = threadIdx.x;
    const int s = blockIdx.y;                                  // o-half
    const float* wsW1 = (const float*)(wsb);
    const float* wsB1 = (const float*)(wsb + 2048);
    const float* wsBf = (const float*)(wsb + 2176);
    const unsigned short* wsAhi = (const unsigned short*)(wsb + 6272);

    // ---- issue per-edge input loads first (long latency, overlap staging) --
    int e = blockIdx.x * EPB + t;
    int ec = (e < nE) ? e : (nE - 1);
    int my_src = __builtin_nontemporal_load(eidx + ec);
    int my_dst = __builtin_nontemporal_load(eidx + nE + ec);

    const v4f* xrow_p = (const v4f*)(x + (size_t)my_src * HD);
    v4f xrow[8];
#pragma unroll
    for (int q = 0; q < 8; ++q) xrow[q] = xrow_p[q];

    const v4f* eap = (const v4f*)(ea_g + (size_t)ec * ED);
    v4f a0 = __builtin_nontemporal_load(eap + 0);
    v4f a1 = __builtin_nontemporal_load(eap + 1);
    v4f a2 = __builtin_nontemporal_load(eap + 2);
    v4f a3 = __builtin_nontemporal_load(eap + 3);

    srcS[t] = my_src;
    dstS[t] = my_dst;

    // ---- stage small tables ----
    if (t < 128)       ((v4f*)w1t)[t] = ((const v4f*)wsW1)[t];
    else if (t < 136)  ((v4f*)b1s)[t - 128] = ((const v4f*)wsB1)[t - 128];
    else if (t < 264) {   // bias half: bfL[i*16+m] = bfold[i*32 + s*16 + m]
        int d = t - 136;
        ((v4f*)bfL)[d] = ((const v4f*)wsBf)[(d >> 2) * 8 + s * 4 + (d & 3)];
    }

    // ---- stage this o-half's hi weight frags: 4 v4f per thread (32 KB) ----
    {
        const v4f* srcHi = (const v4f*)wsAhi;    // v4f = 8 halfwords
        v4f* dstHi = (v4f*)wLhi;
#pragma unroll
        for (int p = 0; p < 4; ++p) {
            int c = t + p * 512;                          // dst v4f: i = c>>6, lane = c&63
            int sc = (2 * (c >> 6) + s) * 64 + (c & 63);  // src v4f: g*64 + lane
            dstHi[c] = srcHi[sc];
        }
    }

    __syncthreads();   // (1) tables + weights ready

    // ---- layer 1 into registers ----
    float hreg[HD];
#pragma unroll
    for (int c = 0; c < HD; ++c) {
        const v4f* r4 = (const v4f*)(w1t + c * ED);
        v4f w0 = r4[0], w1 = r4[1], w2 = r4[2], w3 = r4[3];
        float acc = b1s[c];
        acc = fmaf(a0.x, w0.x, acc); acc = fmaf(a0.y, w0.y, acc);
        acc = fmaf(a0.z, w0.z, acc); acc = fmaf(a0.w, w0.w, acc);
        acc = fmaf(a1.x, w1.x, acc); acc = fmaf(a1.y, w1.y, acc);
        acc = fmaf(a1.z, w1.z, acc); acc = fmaf(a1.w, w1.w, acc);
        acc = fmaf(a2.x, w2.x, acc); acc = fmaf(a2.y, w2.y, acc);
        acc = fmaf(a2.z, w2.z, acc); acc = fmaf(a2.w, w2.w, acc);
        acc = fmaf(a3.x, w3.x, acc); acc = fmaf(a3.y, w3.y, acc);
        acc = fmaf(a3.z, w3.z, acc); acc = fmaf(a3.w, w3.w, acc);
        hreg[c] = fmaxf(acc, 0.01f * acc);
    }

    // ---- pack h (hi only, RNE) to LDS rows ----
#pragma unroll
    for (int ch = 0; ch < 4; ++ch) {
        bf16x8 phi;
#pragma unroll
        for (int u = 0; u < 8; ++u)
            phi[u] = (short)bf16_rne(hreg[ch * 8 + u]);
        *(bf16x8*)(hHi + t * HPAD + ch * 8) = phi;
    }
    __syncthreads();   // (2) h ready

    // ---- B-frags LDS -> regs ----
    const int wave = t >> 6;
    const int lane = t & 63;
    const int n = lane & 15;       // C column = edge within tile
    const int quad = lane >> 4;
    const int ebase = wave * 64;   // wave's first edge in block

    bf16x8 bHi[TPW];
#pragma unroll
    for (int tt = 0; tt < TPW; ++tt) {
        int edge = ebase + tt * 16 + n;
        bHi[tt] = *(const bf16x8*)(hHi + edge * HPAD + quad * 8);
    }

    int xdst[TPW];
    bool evalid[TPW];
    int xoff[TPW];
#pragma unroll
    for (int tt = 0; tt < TPW; ++tt) {
        int le = ebase + tt * 16 + n;
        evalid[tt] = (blockIdx.x * EPB + le) < nE;
        xdst[tt] = dstS[le];
        xoff[tt] = le * HPAD;
    }

    __syncthreads();   // (3) everyone done reading h LDS

    // ---- overlay: write x rows (bf16 RNE) into xS ----
#pragma unroll
    for (int ch = 0; ch < 4; ++ch) {
        bf16x8 px;
#pragma unroll
        for (int u = 0; u < 8; ++u) {
            int q = ch * 2 + (u >> 2);
            px[u] = (short)bf16_rne(xrow[q][u & 3]);
        }
        *(bf16x8*)(xS + t * HPAD + ch * 8) = px;
    }
    __syncthreads();   // (4) xS ready

    f32x4 msg[TPW];
#pragma unroll
    for (int tt = 0; tt < TPW; ++tt)
        msg[tt] = (f32x4){0.f, 0.f, 0.f, 0.f};

    // ---- main loop: pure LDS + MFMA (1 MFMA per tile) ----
#pragma unroll 4
    for (int i = 0; i < HD; ++i) {
        const bf16x8 cH = *(const bf16x8*)(wLhi + i * 512 + lane * 8);
        const f32x4 b0 = *(const f32x4*)(bfL + i * 16 + quad * 4);
        float xv[TPW];
#pragma unroll
        for (int tt = 0; tt < TPW; ++tt) {
            unsigned int u = xS[xoff[tt] + i];
            xv[tt] = __uint_as_float(u << 16);
        }

#pragma unroll
        for (int tt = 0; tt < TPW; ++tt) {
            f32x4 c = b0;
            c = __builtin_amdgcn_mfma_f32_16x16x32_bf16(cH, bHi[tt], c, 0, 0, 0);
            f32x4 w = __builtin_elementwise_max(c, 0.01f * c);   // LeakyReLU
            f32x4 xs = {xv[tt], xv[tt], xv[tt], xv[tt]};
            msg[tt] = __builtin_elementwise_fma(xs, w, msg[tt]);
        }
    }

    // ---- scatter: out[dst][o], o = s*16 + quad*4 + r ----
#pragma unroll
    for (int tt = 0; tt < TPW; ++tt) {
        if (!evalid[tt]) continue;
        float* op = out + (size_t)xdst[tt] * OD + s * 16 + quad * 4;
#pragma unroll
        for (int r = 0; r < 4; ++r)
            atomicAdd(op + r, msg[tt][r]);
    }
}

// ---------------------------------------------------------------------------
// Fallback (ws too small): correctness path only (VALU, raw weights).
// ---------------------------------------------------------------------------
__global__ __launch_bounds__(64)
void edge_kernel_raw(const float* __restrict__ x, const int* __restrict__ eidx,
                     const float* __restrict__ ea_g,
                     const float* __restrict__ W1, const float* __restrict__ b1,
                     const float* __restrict__ g1, const float* __restrict__ be1,
                     const float* __restrict__ m1, const float* __restrict__ v1,
                     const float* __restrict__ W2, const float* __restrict__ b2,
                     const float* __restrict__ g2, const float* __restrict__ be2,
                     const float* __restrict__ m2, const float* __restrict__ v2,
                     float* __restrict__ out, int nE)
{
    int e = blockIdx.x * 64 + threadIdx.x;
    if (e >= nE) return;
    const int obase = blockIdx.y * 16;

    int src = eidx[e];
    int dst = eidx[nE + e];

    float ea[ED];
#pragma unroll
    for (int j = 0; j < ED; ++j) ea[j] = ea_g[(size_t)e * ED + j];

    float h[HD];
#pragma unroll
    for (int c = 0; c < HD; ++c) {
        float acc = b1[c];
#pragma unroll
        for (int j = 0; j < ED; ++j) acc = fmaf(ea[j], W1[j * HD + c], acc);
        float s = g1[c] / sqrtf(v1[c] + 1e-5f);
        acc = (acc - m1[c]) * s + be1[c];
        h[c] = fmaxf(acc, 0.01f * acc);
    }

    float msg[16];
#pragma unroll
    for (int o = 0; o < 16; ++o) msg[o] = 0.f;

    const float* xj = x + (size_t)src * HD;
    for (int i = 0; i < HD; ++i) {
        float xv = xj[i];
#pragma unroll
        for (int oo = 0; oo < 16; ++oo) {
            int k = i * OD + obase + oo;
            float acc = b2[k];
#pragma unroll
            for (int j = 0; j < HD; ++j) acc = fmaf(h[j], W2[j * KD + k], acc);
            float s = g2[k] / sqrtf(v2[k] + 1e-5f);
            acc = (acc - m2[k]) * s + be2[k];
            float w = fmaxf(acc, 0.01f * acc);
            msg[oo] = fmaf(xv, w, msg[oo]);
        }
    }

    float* op = out + (size_t)dst * OD + obase;
#pragma unroll
    for (int oo = 0; oo < 16; ++oo) atomicAdd(op + oo, msg[oo]);
}

// ---------------------------------------------------------------------------
extern "C" void kernel_launch(void* const* d_in, const int* in_sizes, int n_in,
                              void* d_out, int out_size, void* d_ws, size_t ws_size,
                              hipStream_t stream)
{
    const float* x    = (const float*)d_in[0];
    const int*   eidx = (const int*)  d_in[1];
    const float* ea   = (const float*)d_in[2];
    // d_in[3] = batch (unused)
    const float* W1   = (const float*)d_in[4];
    const float* b1   = (const float*)d_in[5];
    const float* g1   = (const float*)d_in[6];
    const float* be1  = (const float*)d_in[7];
    const float* m1   = (const float*)d_in[8];
    const float* v1   = (const float*)d_in[9];
    const float* W2   = (const float*)d_in[10];
    const float* b2   = (const float*)d_in[11];
    const float* g2   = (const float*)d_in[12];
    const float* be2  = (const float*)d_in[13];
    const float* m2   = (const float*)d_in[14];
    const float* v2   = (const float*)d_in[15];
    const float* root = (const float*)d_in[16];
    const float* bias = (const float*)d_in[17];
    float* out = (float*)d_out;

    int nN = in_sizes[0] / HD;
    int nE = in_sizes[2] / ED;

    if (ws_size >= WS_BYTES) {
        unsigned char* wsb = (unsigned char*)d_ws;
        int nRootBlk = (nN + 7) / 8;
        prep_root_kernel<<<dim3(nRootBlk + 128), 256, 0, stream>>>(
            x, root, bias, out, nN, nRootBlk,
            W1, b1, g1, be1, m1, v1, W2, b2, g2, be2, m2, v2, wsb);
        int nblk = (nE + EPB - 1) / EPB;
        edge_kernel<<<dim3(nblk, 2), 512, 0, stream>>>(x, eidx, ea, wsb, out, nE);
    } else {
        prep_root_kernel<<<dim3((nN + 7) / 8), 256, 0, stream>>>(
            x, root, bias, out, nN, (nN + 7) / 8 + 1,   // root path only
            W1, b1, g1, be1, m1, v1, W2, b2, g2, be2, m2, v2, (unsigned char*)d_ws);
        edge_kernel_raw<<<dim3((nE + 63) / 64, 2), 64, 0, stream>>>(
            x, eidx, ea, W1, b1, g1, be1, m1, v1,
            W2, b2, g2, be2, m2, v2, out, nE);
    }
}

// Round 10
// 203.945 us; speedup vs baseline: 1.3130x; 1.0555x over previous
//
#include <hip/hip_runtime.h>
#include <math.h>

// Problem dims (fixed by the reference)
#define ED 16      // EDGE_DIM
#define HD 32      // HIDDEN (== NODE_DIM == in_channels)
#define OD 32      // OUT_DIM
#define KD 1024    // HD*OD
#define EPB 512    // edges per block (8 waves, one o-half per block)
#define TPW 4      // 16-edge tiles per wave
#define HPAD 34    // LDS row stride in halfwords: odd word-stride -> conflict-free
#define CAP 32     // bucket capacity per node (deg ~Poisson(4); overflow -> atomic path)

typedef float  f32x4  __attribute__((ext_vector_type(4)));
typedef float  v4f    __attribute__((ext_vector_type(4)));
typedef short  bf16x8 __attribute__((ext_vector_type(8)));

// Workspace layout (byte offsets; all 16B aligned)
//  [0)      W1fT   512 f32 ; [2048) b1f 32 f32 ; [2176) bfold 1024 f32
//  [6272)   wsAhi 32768 bf16 W2fT hi (RNE), frag-linear
//  [72064)  msg   [nE][32] f32      (two-phase path)
//  [+nE*128) bucket [nN][CAP] int
//  [+nN*128) cnt  [nN] int
constexpr size_t WS_WEIGHTS = 71808;
constexpr size_t OFF_MSG = 72064;

// LDS layout for edge_kernel (unchanged from r9): 75904 B -> 2 blocks/CU.
constexpr int LOFF_HX   = 0;
constexpr int LOFF_WHI  = EPB * HPAD * 2;            // 34816
constexpr int LOFF_W1T  = LOFF_WHI + 32768;          // 67584
constexpr int LOFF_B1   = LOFF_W1T + 2048;           // 69632
constexpr int LOFF_BF   = LOFF_B1 + 128;             // 69760
constexpr int LOFF_SRC  = LOFF_BF + 2048;            // 71808
constexpr int LOFF_DST  = LOFF_SRC + 2048;           // 73856
constexpr int LDS_TOTAL = LOFF_DST + 2048;           // 75904

__device__ inline unsigned short bf16_rne(float v) {
    unsigned int u = __float_as_uint(v);
    return (unsigned short)((u + 0x7FFFu + ((u >> 16) & 1u)) >> 16);
}

// ---------------------------------------------------------------------------
// Fused prep+root kernel (same as r9).
// ---------------------------------------------------------------------------
__global__ __launch_bounds__(256)
void prep_root_kernel(const float* __restrict__ x, const float* __restrict__ root,
                      const float* __restrict__ bias, float* __restrict__ out, int nN,
                      int nRootBlk,
                      const float* __restrict__ W1, const float* __restrict__ b1,
                      const float* __restrict__ g1, const float* __restrict__ be1,
                      const float* __restrict__ m1, const float* __restrict__ v1,
                      const float* __restrict__ W2, const float* __restrict__ b2,
                      const float* __restrict__ g2, const float* __restrict__ be2,
                      const float* __restrict__ m2, const float* __restrict__ v2,
                      unsigned char* __restrict__ wsb)
{
    const int t = threadIdx.x;
    if ((int)blockIdx.x >= nRootBlk) {
        float* w1t = (float*)(wsb);
        float* b1f = (float*)(wsb + 2048);
        float* bf  = (float*)(wsb + 2176);
        unsigned short* ahi = (unsigned short*)(wsb + 6272);

        int bt = ((int)blockIdx.x - nRootBlk) * blockDim.x + t;
        int stride = 128 * blockDim.x;

        for (int q = bt; q < HD * ED; q += stride) {
            int c = q >> 4, j = q & 15;
            float s = g1[c] / sqrtf(v1[c] + 1e-5f);
            w1t[q] = W1[j * HD + c] * s;
        }
        for (int c = bt; c < HD; c += stride) {
            float s = g1[c] / sqrtf(v1[c] + 1e-5f);
            b1f[c] = b1[c] * s + be1[c] - m1[c] * s;
        }
        for (int k = bt; k < KD; k += stride) {
            float s = g2[k] / sqrtf(v2[k] + 1e-5f);
            bf[k] = b2[k] * s + be2[k] - m2[k] * s;
        }
        for (int p = bt; p < KD * HD; p += stride) {
            int j = p >> 10, k = p & 1023;
            float s = g2[k] / sqrtf(v2[k] + 1e-5f);
            float v = W2[p] * s;
            int g = k >> 4, m = k & 15;
            int quad = j >> 3, idx = j & 7;
            int q = g * 512 + (quad * 16 + m) * 8 + idx;
            ahi[q] = bf16_rne(v);
        }
        return;
    }

    __shared__ __align__(16) float rootS[HD * OD];
    __shared__ __align__(16) float biasS[OD];
    __shared__ float xsh[8][HD + 1];

    ((v4f*)rootS)[t] = ((const v4f*)root)[t];
    if (t < 8) ((v4f*)biasS)[t] = ((const v4f*)bias)[t];

    const int nodeBase = blockIdx.x * 8;
    if (t < 64) {
        int nl = t >> 3, q = t & 7;
        int node = nodeBase + nl;
        if (node >= nN) node = nN - 1;
        v4f v = ((const v4f*)(x + (size_t)node * HD))[q];
        xsh[nl][4 * q + 0] = v.x;
        xsh[nl][4 * q + 1] = v.y;
        xsh[nl][4 * q + 2] = v.z;
        xsh[nl][4 * q + 3] = v.w;
    }
    __syncthreads();

    const int nl = t >> 5, o = t & 31;
    const int node = nodeBase + nl;
    if (node >= nN) return;
    float acc = biasS[o];
#pragma unroll
    for (int i = 0; i < HD; ++i)
        acc = fmaf(xsh[nl][i], rootS[i * OD + o], acc);
    out[(size_t)node * OD + o] = acc;
}

// ---------------------------------------------------------------------------
// Edge kernel v10: r9 body, but epilogue writes per-edge messages to msg[E][32]
// with non-temporal coalesced stores — NO atomics (templated on MSG).
// ---------------------------------------------------------------------------
template <bool MSG>
__global__ __launch_bounds__(512, 4)
void edge_kernel(const float* __restrict__ x, const int* __restrict__ eidx,
                 const float* __restrict__ ea_g, const unsigned char* __restrict__ wsb,
                 float* __restrict__ outm, int nE)
{
    __shared__ __align__(16) unsigned char smem[LDS_TOTAL];
    unsigned short* hHi = (unsigned short*)(smem + LOFF_HX);
    unsigned short* xS  = (unsigned short*)(smem + LOFF_HX);
    unsigned short* wLhi = (unsigned short*)(smem + LOFF_WHI);
    float* w1t = (float*)(smem + LOFF_W1T);
    float* b1s = (float*)(smem + LOFF_B1);
    float* bfL = (float*)(smem + LOFF_BF);
    int*  srcS = (int*)(smem + LOFF_SRC);
    int*  dstS = (int*)(smem + LOFF_DST);

    const int t = threadIdx.x;
    const int s = blockIdx.y;
    const float* wsW1 = (const float*)(wsb);
    const float* wsB1 = (const float*)(wsb + 2048);
    const float* wsBf = (const float*)(wsb + 2176);
    const unsigned short* wsAhi = (const unsigned short*)(wsb + 6272);

    int e = blockIdx.x * EPB + t;
    int ec = (e < nE) ? e : (nE - 1);
    int my_src = __builtin_nontemporal_load(eidx + ec);
    int my_dst = __builtin_nontemporal_load(eidx + nE + ec);

    const v4f* xrow_p = (const v4f*)(x + (size_t)my_src * HD);
    v4f xrow[8];
#pragma unroll
    for (int q = 0; q < 8; ++q) xrow[q] = xrow_p[q];

    const v4f* eap = (const v4f*)(ea_g + (size_t)ec * ED);
    v4f a0 = __builtin_nontemporal_load(eap + 0);
    v4f a1 = __builtin_nontemporal_load(eap + 1);
    v4f a2 = __builtin_nontemporal_load(eap + 2);
    v4f a3 = __builtin_nontemporal_load(eap + 3);

    srcS[t] = my_src;
    dstS[t] = my_dst;

    if (t < 128)       ((v4f*)w1t)[t] = ((const v4f*)wsW1)[t];
    else if (t < 136)  ((v4f*)b1s)[t - 128] = ((const v4f*)wsB1)[t - 128];
    else if (t < 264) {
        int d = t - 136;
        ((v4f*)bfL)[d] = ((const v4f*)wsBf)[(d >> 2) * 8 + s * 4 + (d & 3)];
    }

    {
        const v4f* srcHi = (const v4f*)wsAhi;
        v4f* dstHi = (v4f*)wLhi;
#pragma unroll
        for (int p = 0; p < 4; ++p) {
            int c = t + p * 512;
            int sc = (2 * (c >> 6) + s) * 64 + (c & 63);
            dstHi[c] = srcHi[sc];
        }
    }

    __syncthreads();

    float hreg[HD];
#pragma unroll
    for (int c = 0; c < HD; ++c) {
        const v4f* r4 = (const v4f*)(w1t + c * ED);
        v4f w0 = r4[0], w1 = r4[1], w2 = r4[2], w3 = r4[3];
        float acc = b1s[c];
        acc = fmaf(a0.x, w0.x, acc); acc = fmaf(a0.y, w0.y, acc);
        acc = fmaf(a0.z, w0.z, acc); acc = fmaf(a0.w, w0.w, acc);
        acc = fmaf(a1.x, w1.x, acc); acc = fmaf(a1.y, w1.y, acc);
        acc = fmaf(a1.z, w1.z, acc); acc = fmaf(a1.w, w1.w, acc);
        acc = fmaf(a2.x, w2.x, acc); acc = fmaf(a2.y, w2.y, acc);
        acc = fmaf(a2.z, w2.z, acc); acc = fmaf(a2.w, w2.w, acc);
        acc = fmaf(a3.x, w3.x, acc); acc = fmaf(a3.y, w3.y, acc);
        acc = fmaf(a3.z, w3.z, acc); acc = fmaf(a3.w, w3.w, acc);
        hreg[c] = fmaxf(acc, 0.01f * acc);
    }

#pragma unroll
    for (int ch = 0; ch < 4; ++ch) {
        bf16x8 phi;
#pragma unroll
        for (int u = 0; u < 8; ++u)
            phi[u] = (short)bf16_rne(hreg[ch * 8 + u]);
        *(bf16x8*)(hHi + t * HPAD + ch * 8) = phi;
    }
    __syncthreads();

    const int wave = t >> 6;
    const int lane = t & 63;
    const int n = lane & 15;
    const int quad = lane >> 4;
    const int ebase = wave * 64;

    bf16x8 bHi[TPW];
#pragma unroll
    for (int tt = 0; tt < TPW; ++tt) {
        int edge = ebase + tt * 16 + n;
        bHi[tt] = *(const bf16x8*)(hHi + edge * HPAD + quad * 8);
    }

    int xdst[TPW];
    bool evalid[TPW];
    int xoff[TPW];
    int geid[TPW];
#pragma unroll
    for (int tt = 0; tt < TPW; ++tt) {
        int le = ebase + tt * 16 + n;
        geid[tt] = blockIdx.x * EPB + le;
        evalid[tt] = geid[tt] < nE;
        xdst[tt] = dstS[le];
        xoff[tt] = le * HPAD;
    }

    __syncthreads();

#pragma unroll
    for (int ch = 0; ch < 4; ++ch) {
        bf16x8 px;
#pragma unroll
        for (int u = 0; u < 8; ++u) {
            int q = ch * 2 + (u >> 2);
            px[u] = (short)bf16_rne(xrow[q][u & 3]);
        }
        *(bf16x8*)(xS + t * HPAD + ch * 8) = px;
    }
    __syncthreads();

    f32x4 msg[TPW];
#pragma unroll
    for (int tt = 0; tt < TPW; ++tt)
        msg[tt] = (f32x4){0.f, 0.f, 0.f, 0.f};

#pragma unroll 4
    for (int i = 0; i < HD; ++i) {
        const bf16x8 cH = *(const bf16x8*)(wLhi + i * 512 + lane * 8);
        const f32x4 b0 = *(const f32x4*)(bfL + i * 16 + quad * 4);
        float xv[TPW];
#pragma unroll
        for (int tt = 0; tt < TPW; ++tt) {
            unsigned int u = xS[xoff[tt] + i];
            xv[tt] = __uint_as_float(u << 16);
        }

#pragma unroll
        for (int tt = 0; tt < TPW; ++tt) {
            f32x4 c = b0;
            c = __builtin_amdgcn_mfma_f32_16x16x32_bf16(cH, bHi[tt], c, 0, 0, 0);
            f32x4 w = __builtin_elementwise_max(c, 0.01f * c);
            f32x4 xs = {xv[tt], xv[tt], xv[tt], xv[tt]};
            msg[tt] = __builtin_elementwise_fma(xs, w, msg[tt]);
        }
    }

    if (MSG) {
        // outm = msg buffer [nE][32]; this y-half owns channels [16s,16s+16)
#pragma unroll
        for (int tt = 0; tt < TPW; ++tt) {
            if (!evalid[tt]) continue;
            float* mp = outm + (size_t)geid[tt] * OD + s * 16 + quad * 4;
            __builtin_nontemporal_store(msg[tt], (f32x4*)mp);
        }
    } else {
        // outm = out; atomic fallback path
#pragma unroll
        for (int tt = 0; tt < TPW; ++tt) {
            if (!evalid[tt]) continue;
            float* op = outm + (size_t)xdst[tt] * OD + s * 16 + quad * 4;
#pragma unroll
            for (int r = 0; r < 4; ++r)
                atomicAdd(op + r, msg[tt][r]);
        }
    }
}

// ---------------------------------------------------------------------------
// zero cnt
// ---------------------------------------------------------------------------
__global__ void zero_cnt_kernel(int* __restrict__ cnt, int nN)
{
    int t = blockIdx.x * blockDim.x + threadIdx.x;
    if (t < nN) cnt[t] = 0;
}

// ---------------------------------------------------------------------------
// bucket edges by dst. Overflow (>CAP, ~never for Poisson(4)): direct atomic
// add of the edge's msg row into out (msg kernel has already completed).
// ---------------------------------------------------------------------------
__global__ void bucket_kernel(const int* __restrict__ eidx,
                              const float* __restrict__ msg,
                              float* __restrict__ out,
                              int* __restrict__ cnt, int* __restrict__ bucket, int nE)
{
    int e = blockIdx.x * blockDim.x + threadIdx.x;
    if (e >= nE) return;
    int dst = eidx[nE + e];
    int pos = atomicAdd(cnt + dst, 1);
    if (pos < CAP) {
        bucket[(size_t)dst * CAP + pos] = e;
    } else {
        const float* mp = msg + (size_t)e * OD;
        float* op = out + (size_t)dst * OD;
#pragma unroll
        for (int ch = 0; ch < OD; ++ch) atomicAdd(op + ch, mp[ch]);
    }
}

// ---------------------------------------------------------------------------
// gather: per (node, ch), sum msg rows of the node's bucket, add into out
// (out already holds x@root + bias + any overflow atomics). Plain stores.
// ---------------------------------------------------------------------------
__global__ __launch_bounds__(256)
void gather_kernel(const float* __restrict__ msg, const int* __restrict__ bucket,
                   const int* __restrict__ cnt, float* __restrict__ out, int nN)
{
    int t = threadIdx.x;
    int v = blockIdx.x * 8 + (t >> 5);
    int ch = t & 31;
    if (v >= nN) return;
    int c = cnt[v];
    if (c > CAP) c = CAP;
    const int* bk = bucket + (size_t)v * CAP;
    float acc = 0.f;
    for (int p = 0; p < c; ++p) {
        int e = bk[p];
        acc += msg[(size_t)e * OD + ch];
    }
    out[(size_t)v * OD + ch] += acc;
}

// ---------------------------------------------------------------------------
// Fallback (ws too small): correctness path only (VALU, raw weights).
// ---------------------------------------------------------------------------
__global__ __launch_bounds__(64)
void edge_kernel_raw(const float* __restrict__ x, const int* __restrict__ eidx,
                     const float* __restrict__ ea_g,
                     const float* __restrict__ W1, const float* __restrict__ b1,
                     const float* __restrict__ g1, const float* __restrict__ be1,
                     const float* __restrict__ m1, const float* __restrict__ v1,
                     const float* __restrict__ W2, const float* __restrict__ b2,
                     const float* __restrict__ g2, const float* __restrict__ be2,
                     const float* __restrict__ m2, const float* __restrict__ v2,
                     float* __restrict__ out, int nE)
{
    int e = blockIdx.x * 64 + threadIdx.x;
    if (e >= nE) return;
    const int obase = blockIdx.y * 16;

    int src = eidx[e];
    int dst = eidx[nE + e];

    float ea[ED];
#pragma unroll
    for (int j = 0; j < ED; ++j) ea[j] = ea_g[(size_t)e * ED + j];

    float h[HD];
#pragma unroll
    for (int c = 0; c < HD; ++c) {
        float acc = b1[c];
#pragma unroll
        for (int j = 0; j < ED; ++j) acc = fmaf(ea[j], W1[j * HD + c], acc);
        float s = g1[c] / sqrtf(v1[c] + 1e-5f);
        acc = (acc - m1[c]) * s + be1[c];
        h[c] = fmaxf(acc, 0.01f * acc);
    }

    float msg[16];
#pragma unroll
    for (int o = 0; o < 16; ++o) msg[o] = 0.f;

    const float* xj = x + (size_t)src * HD;
    for (int i = 0; i < HD; ++i) {
        float xv = xj[i];
#pragma unroll
        for (int oo = 0; oo < 16; ++oo) {
            int k = i * OD + obase + oo;
            float acc = b2[k];
#pragma unroll
            for (int j = 0; j < HD; ++j) acc = fmaf(h[j], W2[j * KD + k], acc);
            float s = g2[k] / sqrtf(v2[k] + 1e-5f);
            acc = (acc - m2[k]) * s + be2[k];
            float w = fmaxf(acc, 0.01f * acc);
            msg[oo] = fmaf(xv, w, msg[oo]);
        }
    }

    float* op = out + (size_t)dst * OD + obase;
#pragma unroll
    for (int oo = 0; oo < 16; ++oo) atomicAdd(op + oo, msg[oo]);
}

// ---------------------------------------------------------------------------
extern "C" void kernel_launch(void* const* d_in, const int* in_sizes, int n_in,
                              void* d_out, int out_size, void* d_ws, size_t ws_size,
                              hipStream_t stream)
{
    const float* x    = (const float*)d_in[0];
    const int*   eidx = (const int*)  d_in[1];
    const float* ea   = (const float*)d_in[2];
    const float* W1   = (const float*)d_in[4];
    const float* b1   = (const float*)d_in[5];
    const float* g1   = (const float*)d_in[6];
    const float* be1  = (const float*)d_in[7];
    const float* m1   = (const float*)d_in[8];
    const float* v1   = (const float*)d_in[9];
    const float* W2   = (const float*)d_in[10];
    const float* b2   = (const float*)d_in[11];
    const float* g2   = (const float*)d_in[12];
    const float* be2  = (const float*)d_in[13];
    const float* m2   = (const float*)d_in[14];
    const float* v2   = (const float*)d_in[15];
    const float* root = (const float*)d_in[16];
    const float* bias = (const float*)d_in[17];
    float* out = (float*)d_out;

    int nN = in_sizes[0] / HD;
    int nE = in_sizes[2] / ED;

    size_t msgB = (size_t)nE * OD * 4;
    size_t bktB = (size_t)nN * CAP * 4;
    size_t OFF_BKT = OFF_MSG + msgB;
    size_t OFF_CNT = OFF_BKT + bktB;
    size_t needTwoPhase = OFF_CNT + (size_t)nN * 4;

    if (ws_size >= needTwoPhase) {
        unsigned char* wsb = (unsigned char*)d_ws;
        float* msg  = (float*)(wsb + OFF_MSG);
        int* bucket = (int*)(wsb + OFF_BKT);
        int* cnt    = (int*)(wsb + OFF_CNT);

        int nRootBlk = (nN + 7) / 8;
        prep_root_kernel<<<dim3(nRootBlk + 128), 256, 0, stream>>>(
            x, root, bias, out, nN, nRootBlk,
            W1, b1, g1, be1, m1, v1, W2, b2, g2, be2, m2, v2, wsb);
        zero_cnt_kernel<<<(nN + 1023) / 1024, 1024, 0, stream>>>(cnt, nN);
        int nblk = (nE + EPB - 1) / EPB;
        edge_kernel<true><<<dim3(nblk, 2), 512, 0, stream>>>(x, eidx, ea, wsb, msg, nE);
        bucket_kernel<<<(nE + 255) / 256, 256, 0, stream>>>(eidx, msg, out, cnt, bucket, nE);
        gather_kernel<<<(nN + 7) / 8, 256, 0, stream>>>(msg, bucket, cnt, out, nN);
    } else if (ws_size >= WS_WEIGHTS) {
        unsigned char* wsb = (unsigned char*)d_ws;
        int nRootBlk = (nN + 7) / 8;
        prep_root_kernel<<<dim3(nRootBlk + 128), 256, 0, stream>>>(
            x, root, bias, out, nN, nRootBlk,
            W1, b1, g1, be1, m1, v1, W2, b2, g2, be2, m2, v2, wsb);
        int nblk = (nE + EPB - 1) / EPB;
        edge_kernel<false><<<dim3(nblk, 2), 512, 0, stream>>>(x, eidx, ea, wsb, out, nE);
    } else {
        prep_root_kernel<<<dim3((nN + 7) / 8), 256, 0, stream>>>(
            x, root, bias, out, nN, (nN + 7) / 8 + 1,
            W1, b1, g1, be1, m1, v1, W2, b2, g2, be2, m2, v2, (unsigned char*)d_ws);
        edge_kernel_raw<<<dim3((nE + 63) / 64, 2), 64, 0, stream>>>(
            x, eidx, ea, W1, b1, g1, be1, m1, v1,
            W2, b2, g2, be2, m2, v2, out, nE);
    }
}

// Round 11
// 184.293 us; speedup vs baseline: 1.4530x; 1.1066x over previous
//
#include <hip/hip_runtime.h>
#include <math.h>

// Problem dims (fixed by the reference)
#define ED 16      // EDGE_DIM
#define HD 32      // HIDDEN (== NODE_DIM == in_channels)
#define OD 32      // OUT_DIM
#define KD 1024    // HD*OD
#define EPB 512    // edges per block (8 waves, one o-half per block)
#define TPW 4      // 16-edge tiles per wave
#define HPAD 34    // LDS row stride in halfwords: odd word-stride -> conflict-free
#define CAP 32     // bucket capacity per node (deg ~Poisson(4); overflow -> rescan)

typedef float  f32x4  __attribute__((ext_vector_type(4)));
typedef float  v4f    __attribute__((ext_vector_type(4)));
typedef short  bf16x8 __attribute__((ext_vector_type(8)));
typedef short  bf16x4 __attribute__((ext_vector_type(4)));

// Workspace layout (byte offsets; all 16B aligned)
//  [0)      W1fT 512 f32 ; [2048) b1f 32 f32 ; [2176) bfold 1024 f32
//  [6272)   wsAhi 32768 bf16 W2fT hi (RNE), frag-linear
//  [72064)  msg   [nE][32] bf16   (two-phase path)
//  then     bucket [nN][CAP] int ; cnt [nN] int
constexpr size_t WS_WEIGHTS = 71808;
constexpr size_t OFF_MSG = 72064;

// LDS layout for edge_kernel (unchanged from r9/r10): 75904 B -> 2 blocks/CU.
constexpr int LOFF_HX   = 0;
constexpr int LOFF_WHI  = EPB * HPAD * 2;            // 34816
constexpr int LOFF_W1T  = LOFF_WHI + 32768;          // 67584
constexpr int LOFF_B1   = LOFF_W1T + 2048;           // 69632
constexpr int LOFF_BF   = LOFF_B1 + 128;             // 69760
constexpr int LOFF_SRC  = LOFF_BF + 2048;            // 71808
constexpr int LOFF_DST  = LOFF_SRC + 2048;           // 73856
constexpr int LDS_TOTAL = LOFF_DST + 2048;           // 75904

__device__ inline unsigned short bf16_rne(float v) {
    unsigned int u = __float_as_uint(v);
    return (unsigned short)((u + 0x7FFFu + ((u >> 16) & 1u)) >> 16);
}

// ---------------------------------------------------------------------------
// Prep kernel (128 blocks): BN-fold weights into ws + zero cnt.
// ---------------------------------------------------------------------------
__global__ __launch_bounds__(256)
void prep_kernel(const float* __restrict__ W1, const float* __restrict__ b1,
                 const float* __restrict__ g1, const float* __restrict__ be1,
                 const float* __restrict__ m1, const float* __restrict__ v1,
                 const float* __restrict__ W2, const float* __restrict__ b2,
                 const float* __restrict__ g2, const float* __restrict__ be2,
                 const float* __restrict__ m2, const float* __restrict__ v2,
                 unsigned char* __restrict__ wsb, int* __restrict__ cnt, int nN)
{
    float* w1t = (float*)(wsb);
    float* b1f = (float*)(wsb + 2048);
    float* bf  = (float*)(wsb + 2176);
    unsigned short* ahi = (unsigned short*)(wsb + 6272);

    int bt = blockIdx.x * blockDim.x + threadIdx.x;
    int stride = gridDim.x * blockDim.x;

    for (int q = bt; q < nN; q += stride) cnt[q] = 0;

    for (int q = bt; q < HD * ED; q += stride) {
        int c = q >> 4, j = q & 15;
        float s = g1[c] / sqrtf(v1[c] + 1e-5f);
        w1t[q] = W1[j * HD + c] * s;
    }
    for (int c = bt; c < HD; c += stride) {
        float s = g1[c] / sqrtf(v1[c] + 1e-5f);
        b1f[c] = b1[c] * s + be1[c] - m1[c] * s;
    }
    for (int k = bt; k < KD; k += stride) {
        float s = g2[k] / sqrtf(v2[k] + 1e-5f);
        bf[k] = b2[k] * s + be2[k] - m2[k] * s;
    }
    for (int p = bt; p < KD * HD; p += stride) {
        int j = p >> 10, k = p & 1023;
        float s = g2[k] / sqrtf(v2[k] + 1e-5f);
        float v = W2[p] * s;
        int g = k >> 4, m = k & 15;
        int quad = j >> 3, idx = j & 7;
        int q = g * 512 + (quad * 16 + m) * 8 + idx;
        ahi[q] = bf16_rne(v);
    }
}

// ---------------------------------------------------------------------------
// Edge kernel v11: r10 body; epilogue writes bf16 msg + does bucket-insert
// (owner thread: s==0 && quad==0 holds dst in a register already).
// MSG=false: legacy direct-atomic fallback path.
// ---------------------------------------------------------------------------
template <bool MSG>
__global__ __launch_bounds__(512, 4)
void edge_kernel(const float* __restrict__ x, const int* __restrict__ eidx,
                 const float* __restrict__ ea_g, const unsigned char* __restrict__ wsb,
                 float* __restrict__ out_atomic, unsigned short* __restrict__ msgb,
                 int* __restrict__ cnt, int* __restrict__ bucket, int nE)
{
    __shared__ __align__(16) unsigned char smem[LDS_TOTAL];
    unsigned short* hHi = (unsigned short*)(smem + LOFF_HX);
    unsigned short* xS  = (unsigned short*)(smem + LOFF_HX);
    unsigned short* wLhi = (unsigned short*)(smem + LOFF_WHI);
    float* w1t = (float*)(smem + LOFF_W1T);
    float* b1s = (float*)(smem + LOFF_B1);
    float* bfL = (float*)(smem + LOFF_BF);
    int*  srcS = (int*)(smem + LOFF_SRC);
    int*  dstS = (int*)(smem + LOFF_DST);

    const int t = threadIdx.x;
    const int s = blockIdx.y;
    const float* wsW1 = (const float*)(wsb);
    const float* wsB1 = (const float*)(wsb + 2048);
    const float* wsBf = (const float*)(wsb + 2176);
    const unsigned short* wsAhi = (const unsigned short*)(wsb + 6272);

    int e = blockIdx.x * EPB + t;
    int ec = (e < nE) ? e : (nE - 1);
    int my_src = __builtin_nontemporal_load(eidx + ec);
    int my_dst = __builtin_nontemporal_load(eidx + nE + ec);

    const v4f* xrow_p = (const v4f*)(x + (size_t)my_src * HD);
    v4f xrow[8];
#pragma unroll
    for (int q = 0; q < 8; ++q) xrow[q] = xrow_p[q];

    const v4f* eap = (const v4f*)(ea_g + (size_t)ec * ED);
    v4f a0 = __builtin_nontemporal_load(eap + 0);
    v4f a1 = __builtin_nontemporal_load(eap + 1);
    v4f a2 = __builtin_nontemporal_load(eap + 2);
    v4f a3 = __builtin_nontemporal_load(eap + 3);

    srcS[t] = my_src;
    dstS[t] = my_dst;

    if (t < 128)       ((v4f*)w1t)[t] = ((const v4f*)wsW1)[t];
    else if (t < 136)  ((v4f*)b1s)[t - 128] = ((const v4f*)wsB1)[t - 128];
    else if (t < 264) {
        int d = t - 136;
        ((v4f*)bfL)[d] = ((const v4f*)wsBf)[(d >> 2) * 8 + s * 4 + (d & 3)];
    }

    {
        const v4f* srcHi = (const v4f*)wsAhi;
        v4f* dstHi = (v4f*)wLhi;
#pragma unroll
        for (int p = 0; p < 4; ++p) {
            int c = t + p * 512;
            int sc = (2 * (c >> 6) + s) * 64 + (c & 63);
            dstHi[c] = srcHi[sc];
        }
    }

    __syncthreads();

    float hreg[HD];
#pragma unroll
    for (int c = 0; c < HD; ++c) {
        const v4f* r4 = (const v4f*)(w1t + c * ED);
        v4f w0 = r4[0], w1 = r4[1], w2 = r4[2], w3 = r4[3];
        float acc = b1s[c];
        acc = fmaf(a0.x, w0.x, acc); acc = fmaf(a0.y, w0.y, acc);
        acc = fmaf(a0.z, w0.z, acc); acc = fmaf(a0.w, w0.w, acc);
        acc = fmaf(a1.x, w1.x, acc); acc = fmaf(a1.y, w1.y, acc);
        acc = fmaf(a1.z, w1.z, acc); acc = fmaf(a1.w, w1.w, acc);
        acc = fmaf(a2.x, w2.x, acc); acc = fmaf(a2.y, w2.y, acc);
        acc = fmaf(a2.z, w2.z, acc); acc = fmaf(a2.w, w2.w, acc);
        acc = fmaf(a3.x, w3.x, acc); acc = fmaf(a3.y, w3.y, acc);
        acc = fmaf(a3.z, w3.z, acc); acc = fmaf(a3.w, w3.w, acc);
        hreg[c] = fmaxf(acc, 0.01f * acc);
    }

#pragma unroll
    for (int ch = 0; ch < 4; ++ch) {
        bf16x8 phi;
#pragma unroll
        for (int u = 0; u < 8; ++u)
            phi[u] = (short)bf16_rne(hreg[ch * 8 + u]);
        *(bf16x8*)(hHi + t * HPAD + ch * 8) = phi;
    }
    __syncthreads();

    const int wave = t >> 6;
    const int lane = t & 63;
    const int n = lane & 15;
    const int quad = lane >> 4;
    const int ebase = wave * 64;

    bf16x8 bHi[TPW];
#pragma unroll
    for (int tt = 0; tt < TPW; ++tt) {
        int edge = ebase + tt * 16 + n;
        bHi[tt] = *(const bf16x8*)(hHi + edge * HPAD + quad * 8);
    }

    int xdst[TPW];
    bool evalid[TPW];
    int xoff[TPW];
    int geid[TPW];
#pragma unroll
    for (int tt = 0; tt < TPW; ++tt) {
        int le = ebase + tt * 16 + n;
        geid[tt] = blockIdx.x * EPB + le;
        evalid[tt] = geid[tt] < nE;
        xdst[tt] = dstS[le];
        xoff[tt] = le * HPAD;
    }

    __syncthreads();

#pragma unroll
    for (int ch = 0; ch < 4; ++ch) {
        bf16x8 px;
#pragma unroll
        for (int u = 0; u < 8; ++u) {
            int q = ch * 2 + (u >> 2);
            px[u] = (short)bf16_rne(xrow[q][u & 3]);
        }
        *(bf16x8*)(xS + t * HPAD + ch * 8) = px;
    }
    __syncthreads();

    f32x4 msg[TPW];
#pragma unroll
    for (int tt = 0; tt < TPW; ++tt)
        msg[tt] = (f32x4){0.f, 0.f, 0.f, 0.f};

#pragma unroll 4
    for (int i = 0; i < HD; ++i) {
        const bf16x8 cH = *(const bf16x8*)(wLhi + i * 512 + lane * 8);
        const f32x4 b0 = *(const f32x4*)(bfL + i * 16 + quad * 4);
        float xv[TPW];
#pragma unroll
        for (int tt = 0; tt < TPW; ++tt) {
            unsigned int u = xS[xoff[tt] + i];
            xv[tt] = __uint_as_float(u << 16);
        }

#pragma unroll
        for (int tt = 0; tt < TPW; ++tt) {
            f32x4 c = b0;
            c = __builtin_amdgcn_mfma_f32_16x16x32_bf16(cH, bHi[tt], c, 0, 0, 0);
            f32x4 w = __builtin_elementwise_max(c, 0.01f * c);
            f32x4 xs = {xv[tt], xv[tt], xv[tt], xv[tt]};
            msg[tt] = __builtin_elementwise_fma(xs, w, msg[tt]);
        }
    }

    if (MSG) {
        // bf16 msg write: 8 B per (edge, quad) — coalesced within the wave
#pragma unroll
        for (int tt = 0; tt < TPW; ++tt) {
            if (!evalid[tt]) continue;
            bf16x4 pm;
#pragma unroll
            for (int r = 0; r < 4; ++r) pm[r] = (short)bf16_rne(msg[tt][r]);
            __builtin_nontemporal_store(pm,
                (bf16x4*)(msgb + (size_t)geid[tt] * OD + s * 16 + quad * 4));
        }
        // bucket insert: one owner thread per edge (s==0, quad==0)
        if (s == 0 && quad == 0) {
#pragma unroll
            for (int tt = 0; tt < TPW; ++tt) {
                if (!evalid[tt]) continue;
                int pos = atomicAdd(cnt + xdst[tt], 1);
                if (pos < CAP) bucket[(size_t)xdst[tt] * CAP + pos] = geid[tt];
            }
        }
    } else {
#pragma unroll
        for (int tt = 0; tt < TPW; ++tt) {
            if (!evalid[tt]) continue;
            float* op = out_atomic + (size_t)xdst[tt] * OD + s * 16 + quad * 4;
#pragma unroll
            for (int r = 0; r < 4; ++r)
                atomicAdd(op + r, msg[tt][r]);
        }
    }
}

// ---------------------------------------------------------------------------
// Gather+root: out[v][ch] = bias[ch] + x[v]@root[:,ch] + sum of bucketed msg.
// Writes out exactly once (plain nt store, no pre-init needed). Overflow
// (cnt>CAP, practically impossible) -> full rescan of dst list for that node.
// ---------------------------------------------------------------------------
__global__ __launch_bounds__(256)
void gather_root_kernel(const float* __restrict__ x, const float* __restrict__ root,
                        const float* __restrict__ bias,
                        const unsigned short* __restrict__ msgb,
                        const int* __restrict__ bucket, const int* __restrict__ cnt,
                        const int* __restrict__ eidx,
                        float* __restrict__ out, int nN, int nE)
{
    __shared__ __align__(16) float rootS[HD * OD];
    __shared__ __align__(16) float biasS[OD];
    __shared__ float xsh[8][HD + 1];

    const int t = threadIdx.x;
    ((v4f*)rootS)[t] = ((const v4f*)root)[t];
    if (t < 8) ((v4f*)biasS)[t] = ((const v4f*)bias)[t];

    const int nodeBase = blockIdx.x * 8;
    if (t < 64) {
        int nl = t >> 3, q = t & 7;
        int node = nodeBase + nl;
        if (node >= nN) node = nN - 1;
        v4f v = ((const v4f*)(x + (size_t)node * HD))[q];
        xsh[nl][4 * q + 0] = v.x;
        xsh[nl][4 * q + 1] = v.y;
        xsh[nl][4 * q + 2] = v.z;
        xsh[nl][4 * q + 3] = v.w;
    }
    __syncthreads();

    const int nl = t >> 5, ch = t & 31;
    const int v = nodeBase + nl;
    if (v >= nN) return;

    float acc = biasS[ch];
#pragma unroll
    for (int i = 0; i < HD; ++i)
        acc = fmaf(xsh[nl][i], rootS[i * OD + ch], acc);

    int c = cnt[v];
    if (c <= CAP) {
        const int* bk = bucket + (size_t)v * CAP;
        for (int p = 0; p < c; ++p) {
            int e = bk[p];
            unsigned int u = msgb[(size_t)e * OD + ch];
            acc += __uint_as_float(u << 16);
        }
    } else {
        // pathological fallback: scan all edges for dst == v
        const int* dstp = eidx + nE;
        for (int e = 0; e < nE; ++e) {
            if (dstp[e] == v) {
                unsigned int u = msgb[(size_t)e * OD + ch];
                acc += __uint_as_float(u << 16);
            }
        }
    }
    __builtin_nontemporal_store(acc, out + (size_t)v * OD + ch);
}

// ---------------------------------------------------------------------------
// Legacy prep+root (fallback paths only): writes out = x@root+bias and folds
// weights, so edge<false> atomics can accumulate on top.
// ---------------------------------------------------------------------------
__global__ __launch_bounds__(256)
void prep_root_kernel(const float* __restrict__ x, const float* __restrict__ root,
                      const float* __restrict__ bias, float* __restrict__ out, int nN,
                      int nRootBlk,
                      const float* __restrict__ W1, const float* __restrict__ b1,
                      const float* __restrict__ g1, const float* __restrict__ be1,
                      const float* __restrict__ m1, const float* __restrict__ v1,
                      const float* __restrict__ W2, const float* __restrict__ b2,
                      const float* __restrict__ g2, const float* __restrict__ be2,
                      const float* __restrict__ m2, const float* __restrict__ v2,
                      unsigned char* __restrict__ wsb)
{
    const int t = threadIdx.x;
    if ((int)blockIdx.x >= nRootBlk) {
        float* w1t = (float*)(wsb);
        float* b1f = (float*)(wsb + 2048);
        float* bf  = (float*)(wsb + 2176);
        unsigned short* ahi = (unsigned short*)(wsb + 6272);

        int bt = ((int)blockIdx.x - nRootBlk) * blockDim.x + t;
        int stride = 128 * blockDim.x;

        for (int q = bt; q < HD * ED; q += stride) {
            int c = q >> 4, j = q & 15;
            float s = g1[c] / sqrtf(v1[c] + 1e-5f);
            w1t[q] = W1[j * HD + c] * s;
        }
        for (int c = bt; c < HD; c += stride) {
            float s = g1[c] / sqrtf(v1[c] + 1e-5f);
            b1f[c] = b1[c] * s + be1[c] - m1[c] * s;
        }
        for (int k = bt; k < KD; k += stride) {
            float s = g2[k] / sqrtf(v2[k] + 1e-5f);
            bf[k] = b2[k] * s + be2[k] - m2[k] * s;
        }
        for (int p = bt; p < KD * HD; p += stride) {
            int j = p >> 10, k = p & 1023;
            float s = g2[k] / sqrtf(v2[k] + 1e-5f);
            float v = W2[p] * s;
            int g = k >> 4, m = k & 15;
            int quad = j >> 3, idx = j & 7;
            int q = g * 512 + (quad * 16 + m) * 8 + idx;
            ahi[q] = bf16_rne(v);
        }
        return;
    }

    __shared__ __align__(16) float rootS[HD * OD];
    __shared__ __align__(16) float biasS[OD];
    __shared__ float xsh[8][HD + 1];

    ((v4f*)rootS)[t] = ((const v4f*)root)[t];
    if (t < 8) ((v4f*)biasS)[t] = ((const v4f*)bias)[t];

    const int nodeBase = blockIdx.x * 8;
    if (t < 64) {
        int nl = t >> 3, q = t & 7;
        int node = nodeBase + nl;
        if (node >= nN) node = nN - 1;
        v4f v = ((const v4f*)(x + (size_t)node * HD))[q];
        xsh[nl][4 * q + 0] = v.x;
        xsh[nl][4 * q + 1] = v.y;
        xsh[nl][4 * q + 2] = v.z;
        xsh[nl][4 * q + 3] = v.w;
    }
    __syncthreads();

    const int nl = t >> 5, o = t & 31;
    const int node = nodeBase + nl;
    if (node >= nN) return;
    float acc = biasS[o];
#pragma unroll
    for (int i = 0; i < HD; ++i)
        acc = fmaf(xsh[nl][i], rootS[i * OD + o], acc);
    out[(size_t)node * OD + o] = acc;
}

// ---------------------------------------------------------------------------
// Fallback (ws too small): correctness path only (VALU, raw weights).
// ---------------------------------------------------------------------------
__global__ __launch_bounds__(64)
void edge_kernel_raw(const float* __restrict__ x, const int* __restrict__ eidx,
                     const float* __restrict__ ea_g,
                     const float* __restrict__ W1, const float* __restrict__ b1,
                     const float* __restrict__ g1, const float* __restrict__ be1,
                     const float* __restrict__ m1, const float* __restrict__ v1,
                     const float* __restrict__ W2, const float* __restrict__ b2,
                     const float* __restrict__ g2, const float* __restrict__ be2,
                     const float* __restrict__ m2, const float* __restrict__ v2,
                     float* __restrict__ out, int nE)
{
    int e = blockIdx.x * 64 + threadIdx.x;
    if (e >= nE) return;
    const int obase = blockIdx.y * 16;

    int src = eidx[e];
    int dst = eidx[nE + e];

    float ea[ED];
#pragma unroll
    for (int j = 0; j < ED; ++j) ea[j] = ea_g[(size_t)e * ED + j];

    float h[HD];
#pragma unroll
    for (int c = 0; c < HD; ++c) {
        float acc = b1[c];
#pragma unroll
        for (int j = 0; j < ED; ++j) acc = fmaf(ea[j], W1[j * HD + c], acc);
        float s = g1[c] / sqrtf(v1[c] + 1e-5f);
        acc = (acc - m1[c]) * s + be1[c];
        h[c] = fmaxf(acc, 0.01f * acc);
    }

    float msg[16];
#pragma unroll
    for (int o = 0; o < 16; ++o) msg[o] = 0.f;

    const float* xj = x + (size_t)src * HD;
    for (int i = 0; i < HD; ++i) {
        float xv = xj[i];
#pragma unroll
        for (int oo = 0; oo < 16; ++oo) {
            int k = i * OD + obase + oo;
            float acc = b2[k];
#pragma unroll
            for (int j = 0; j < HD; ++j) acc = fmaf(h[j], W2[j * KD + k], acc);
            float s = g2[k] / sqrtf(v2[k] + 1e-5f);
            acc = (acc - m2[k]) * s + be2[k];
            float w = fmaxf(acc, 0.01f * acc);
            msg[oo] = fmaf(xv, w, msg[oo]);
        }
    }

    float* op = out + (size_t)dst * OD + obase;
#pragma unroll
    for (int oo = 0; oo < 16; ++oo) atomicAdd(op + oo, msg[oo]);
}

// ---------------------------------------------------------------------------
extern "C" void kernel_launch(void* const* d_in, const int* in_sizes, int n_in,
                              void* d_out, int out_size, void* d_ws, size_t ws_size,
                              hipStream_t stream)
{
    const float* x    = (const float*)d_in[0];
    const int*   eidx = (const int*)  d_in[1];
    const float* ea   = (const float*)d_in[2];
    const float* W1   = (const float*)d_in[4];
    const float* b1   = (const float*)d_in[5];
    const float* g1   = (const float*)d_in[6];
    const float* be1  = (const float*)d_in[7];
    const float* m1   = (const float*)d_in[8];
    const float* v1   = (const float*)d_in[9];
    const float* W2   = (const float*)d_in[10];
    const float* b2   = (const float*)d_in[11];
    const float* g2   = (const float*)d_in[12];
    const float* be2  = (const float*)d_in[13];
    const float* m2   = (const float*)d_in[14];
    const float* v2   = (const float*)d_in[15];
    const float* root = (const float*)d_in[16];
    const float* bias = (const float*)d_in[17];
    float* out = (float*)d_out;

    int nN = in_sizes[0] / HD;
    int nE = in_sizes[2] / ED;

    size_t msgB = (size_t)nE * OD * 2;                 // bf16
    size_t bktB = (size_t)nN * CAP * 4;
    size_t OFF_BKT = (OFF_MSG + msgB + 15) & ~(size_t)15;
    size_t OFF_CNT = OFF_BKT + bktB;
    size_t needTwoPhase = OFF_CNT + (size_t)nN * 4;

    if (ws_size >= needTwoPhase) {
        unsigned char* wsb = (unsigned char*)d_ws;
        unsigned short* msgb = (unsigned short*)(wsb + OFF_MSG);
        int* bucket = (int*)(wsb + OFF_BKT);
        int* cnt    = (int*)(wsb + OFF_CNT);

        prep_kernel<<<128, 256, 0, stream>>>(
            W1, b1, g1, be1, m1, v1, W2, b2, g2, be2, m2, v2, wsb, cnt, nN);
        int nblk = (nE + EPB - 1) / EPB;
        edge_kernel<true><<<dim3(nblk, 2), 512, 0, stream>>>(
            x, eidx, ea, wsb, nullptr, msgb, cnt, bucket, nE);
        gather_root_kernel<<<(nN + 7) / 8, 256, 0, stream>>>(
            x, root, bias, msgb, bucket, cnt, eidx, out, nN, nE);
    } else if (ws_size >= WS_WEIGHTS) {
        unsigned char* wsb = (unsigned char*)d_ws;
        int nRootBlk = (nN + 7) / 8;
        prep_root_kernel<<<dim3(nRootBlk + 128), 256, 0, stream>>>(
            x, root, bias, out, nN, nRootBlk,
            W1, b1, g1, be1, m1, v1, W2, b2, g2, be2, m2, v2, wsb);
        int nblk = (nE + EPB - 1) / EPB;
        edge_kernel<false><<<dim3(nblk, 2), 512, 0, stream>>>(
            x, eidx, ea, wsb, out, nullptr, nullptr, nullptr, nE);
    } else {
        prep_root_kernel<<<dim3((nN + 7) / 8), 256, 0, stream>>>(
            x, root, bias, out, nN, (nN + 7) / 8 + 1,
            W1, b1, g1, be1, m1, v1, W2, b2, g2, be2, m2, v2, (unsigned char*)d_ws);
        edge_kernel_raw<<<dim3((nE + 63) / 64, 2), 64, 0, stream>>>(
            x, eidx, ea, W1, b1, g1, be1, m1, v1,
            W2, b2, g2, be2, m2, v2, out, nE);
    }
}